// Round 1
// baseline (721.761 us; speedup 1.0000x reference)
//
#include <hip/hip_runtime.h>
#include <cstdint>

#define T_ 32
#define N_ 5000
#define E_ 80000
#define H_ 128
#define HD_ 512
#define C_ 10

typedef _Float16 f16;
typedef f16 f16x8 __attribute__((ext_vector_type(8)));
typedef f16 f16x4 __attribute__((ext_vector_type(4)));
typedef f16 f16x2 __attribute__((ext_vector_type(2)));
typedef float f32x4 __attribute__((ext_vector_type(4)));

#define LDA 136   // padded LDS leading dim in f16
#define NB_ 8     // CSR-build blocks per graph
#define EPS_ (E_ / NB_)  // 10000 edges per block
#define STRIPS 16 // gemm row-strips per graph

__device__ inline int addpk(int a, int b) {
    f16x2 x = __builtin_bit_cast(f16x2, a);
    f16x2 y = __builtin_bit_cast(f16x2, b);
    f16x2 r = x + y;
    return __builtin_bit_cast(int, r);
}

__device__ inline float fast_tanh(float x) {
    return 1.0f - 2.0f / (__expf(2.0f * x) + 1.0f);
}

// ---------------- CSR build, LDS-atomic (no global atomics) ----------------
__global__ __launch_bounds__(256) void k_count(const int* __restrict__ ei, int* __restrict__ part) {
    __shared__ int cnt[N_];
    int blk = blockIdx.x;
    int t = blk & 31, seg = blk >> 5;
    int tid = threadIdx.x;
    for (int i = tid; i < N_; i += 256) cnt[i] = 0;
    __syncthreads();
    const int* dst = ei + (size_t)t * 2 * E_ + E_ + seg * EPS_;
    for (int e = tid * 4; e < EPS_; e += 1024) {
        int4 d = *(const int4*)&dst[e];
        atomicAdd(&cnt[d.x], 1);
        atomicAdd(&cnt[d.y], 1);
        atomicAdd(&cnt[d.z], 1);
        atomicAdd(&cnt[d.w], 1);
    }
    __syncthreads();
    int* p = part + (t * NB_ + seg) * N_;
    for (int i = tid * 4; i < N_; i += 1024) *(int4*)&p[i] = *(const int4*)&cnt[i];
}

__global__ __launch_bounds__(256) void k_scan(int* __restrict__ part, int* __restrict__ ptr,
                                              float* __restrict__ dinv, float* __restrict__ z) {
    int t = blockIdx.x, tid = threadIdx.x;
    __shared__ int red[256];
    int base = t * N_;
    if (tid < 128) z[t * 128 + tid] = 0.0f;   // folded zinit
    int* pp = part + t * NB_ * N_;
    int vals[20];
    int sum = 0;
#pragma unroll
    for (int j = 0; j < 20; ++j) {
        int i = tid * 20 + j;
        int c = 0;
        if (i < N_) {
#pragma unroll
            for (int s = 0; s < NB_; ++s) c += pp[s * N_ + i];
            dinv[base + i] = rsqrtf((float)(c + 1));  // +1 self-loop
        }
        vals[j] = sum;
        sum += c;
    }
    red[tid] = sum;
    __syncthreads();
    for (int off = 1; off < 256; off <<= 1) {
        int v = (tid >= off) ? red[tid - off] : 0;
        __syncthreads();
        red[tid] += v;
        __syncthreads();
    }
    int prev = (tid > 0) ? red[tid - 1] : 0;
#pragma unroll
    for (int j = 0; j < 20; ++j) {
        int i = tid * 20 + j;
        if (i < N_) {
            int start = prev + vals[j];
            ptr[base + i] = start;
            int run = start;
#pragma unroll
            for (int s = 0; s < NB_; ++s) {
                int c = pp[s * N_ + i];
                pp[s * N_ + i] = run;
                run += c;
            }
        }
    }
}

__global__ __launch_bounds__(256) void k_scatter(const int* __restrict__ ei,
                                                 const int* __restrict__ part,
                                                 uint16_t* __restrict__ col) {
    __shared__ int cur[N_];
    int blk = blockIdx.x;
    int t = blk & 31, seg = blk >> 5;
    int tid = threadIdx.x;
    const int* off = part + (t * NB_ + seg) * N_;
    for (int i = tid * 4; i < N_; i += 1024) *(int4*)&cur[i] = *(const int4*)&off[i];
    __syncthreads();
    const int* src = ei + (size_t)t * 2 * E_ + seg * EPS_;
    const int* dst = src + E_;
    uint16_t* cl = col + (size_t)t * E_;
    for (int e = tid * 4; e < EPS_; e += 1024) {
        int4 s4 = *(const int4*)&src[e];
        int4 d4 = *(const int4*)&dst[e];
        cl[atomicAdd(&cur[d4.x], 1)] = (uint16_t)s4.x;
        cl[atomicAdd(&cur[d4.y], 1)] = (uint16_t)s4.y;
        cl[atomicAdd(&cur[d4.z], 1)] = (uint16_t)s4.z;
        cl[atomicAdd(&cur[d4.w], 1)] = (uint16_t)s4.w;
    }
}

// ---------------- weight prep: Wt[l][c][k] = (f16)W_l[k][c] ----------------
__global__ __launch_bounds__(256) void k_wprep(const float* __restrict__ W0,
                                               const float* __restrict__ W1,
                                               const float* __restrict__ W2,
                                               f16* __restrict__ Wt) {
    const float* W = (blockIdx.x == 0) ? W0 : (blockIdx.x == 1) ? W1 : W2;
    f16* dst = Wt + blockIdx.x * 16384;
    for (int idx = threadIdx.x; idx < 16384; idx += 256) {
        int c = idx >> 7, k = idx & 127;
        dst[idx] = (f16)W[k * 128 + c];
    }
}

// ---------------- MFMA GEMM v3: W staged once, loop over row tiles ----------------
template <bool F32IN>
__global__ __launch_bounds__(256) void k_gemm(const void* __restrict__ in_,
                                              const f16* __restrict__ Wt,  // [c][k]
                                              const float* __restrict__ dinv,
                                              f16* __restrict__ g) {
    __shared__ f16 Ws[128 * LDA];
    __shared__ f16 As[64 * LDA];
    int b = blockIdx.x;
    int t = b & 31;
    int strip = b >> 5;
    int tid = threadIdx.x;

    // stage Wt -> Ws ONCE (first barrier is inside the tile loop)
    {
        int c = tid >> 1, hf = tid & 1;
        const f16* src = Wt + c * 128 + hf * 64;
        f16* dst = Ws + c * LDA + hf * 64;
#pragma unroll
        for (int j = 0; j < 8; ++j) *(f16x8*)&dst[j * 8] = *(const f16x8*)&src[j * 8];
    }

    int w = tid >> 6, lane = tid & 63;
    int m = lane & 15, q = lane >> 4;
    int rw = w * 16;
    int sr = tid >> 2, skq = (tid & 3) * 32;   // staging row / k-quarter

    for (int tile = strip; tile < 79; tile += STRIPS) {
        int r0 = tile * 64;
        // stage A
        {
            bool valid = (r0 + sr) < N_;
            f16* dst = As + sr * LDA + skq;
            if (F32IN) {
                const float* src = (const float*)in_ + ((size_t)(t * N_ + r0 + sr)) * H_ + skq;
#pragma unroll
                for (int j = 0; j < 8; ++j) {
                    float4 v = valid ? *(const float4*)&src[j * 4] : make_float4(0.f, 0.f, 0.f, 0.f);
                    dst[j * 4 + 0] = (f16)v.x;
                    dst[j * 4 + 1] = (f16)v.y;
                    dst[j * 4 + 2] = (f16)v.z;
                    dst[j * 4 + 3] = (f16)v.w;
                }
            } else {
                const f16* src = (const f16*)in_ + ((size_t)(t * N_ + r0 + sr)) * H_ + skq;
#pragma unroll
                for (int j = 0; j < 4; ++j) {
                    f16x8 v = {};
                    if (valid) v = *(const f16x8*)&src[j * 8];
                    *(f16x8*)&dst[j * 8] = v;
                }
            }
        }
        __syncthreads();  // A (and Ws on first iter) visible

        f32x4 acc[8];
#pragma unroll
        for (int n = 0; n < 8; ++n) acc[n] = (f32x4){0.f, 0.f, 0.f, 0.f};
#pragma unroll
        for (int kb = 0; kb < 4; ++kb) {
            f16x8 aF = *(const f16x8*)&As[(rw + m) * LDA + kb * 32 + q * 8];
#pragma unroll
            for (int n = 0; n < 8; ++n) {
                f16x8 bF = *(const f16x8*)&Ws[(n * 16 + m) * LDA + kb * 32 + q * 8];
                acc[n] = __builtin_amdgcn_mfma_f32_16x16x32_f16(aF, bF, acc[n], 0, 0, 0);
            }
        }
        __syncthreads();  // done reading As; reuse for epilogue

#pragma unroll
        for (int i = 0; i < 4; ++i) {
            int rr = rw + q * 4 + i;
            int gr = r0 + rr;
            float d = dinv[t * N_ + (gr < N_ ? gr : N_ - 1)];
#pragma unroll
            for (int n = 0; n < 8; ++n)
                As[rr * LDA + n * 16 + m] = (f16)(acc[n][i] * d);
        }
        __syncthreads();
        if (r0 + sr < N_) {
            f16* dst = g + ((size_t)(t * N_ + r0 + sr)) * H_ + skq;
            const f16* src = As + sr * LDA + skq;
#pragma unroll
            for (int j = 0; j < 4; ++j) *(f16x8*)&dst[j * 8] = *(const f16x8*)&src[j * 8];
        }
        __syncthreads();  // As free for next tile's staging
    }
}

// ---------------- CSR gather v2: 4 nodes/wave, direct broadcast col loads, ----------------
// 4 independent gather chains, register reduction, no LDS, no __syncthreads.
// Per wave: 4 consecutive nodes. Lane (q=lane>>4, m=lane&15). Per 16-edge chunk,
// group q handles edges e+q+{0,4,8,12} (col load is same-addr across the 16 lanes
// of a group -> HW broadcast). Butterfly reduce leaves the full row slice in ALL
// lanes, so the epilogue just selects node lane>>4 and emits one contiguous
// 1024-B wave store (4 rows).
__global__ __launch_bounds__(256) void k_aggr(const int* __restrict__ ptr,
                                              const uint16_t* __restrict__ col,
                                              const f16* __restrict__ g,
                                              const float* __restrict__ dinv,
                                              const float* __restrict__ b,
                                              f16* __restrict__ out) {
    int blk = blockIdx.x;
    int t = blk & 31;            // graph (keeps t%8 == blk%8 XCD affinity)
    int nb = blk >> 5;           // 16-node block
    int w = threadIdx.x >> 6;
    int lane = threadIdx.x & 63;
    int q = lane >> 4, m = lane & 15;
    int n0 = nb * 16 + w * 4;    // this wave's first node
    if (n0 >= N_) return;        // tail waves (no barriers in this kernel)
    int base = t * N_;
    const f16* gg = g + (size_t)base * H_;
    const uint16_t* cl = col + (size_t)t * E_;
    int mo = m * 8;

    // hoisted epilogue operands (issue early, overlap with gathers)
    int epn = n0 + (lane >> 4);
    bool epv = epn < N_;
    float dn = epv ? dinv[base + epn] : 0.0f;
    float4 b4a = *(const float4*)&b[mo];
    float4 b4b = *(const float4*)&b[mo + 4];

    f16x8 resv[4];
#pragma unroll
    for (int i = 0; i < 4; ++i) {
        int n = n0 + i;
        bool nv = n < N_;
        int begin = 0, end = 0;
        if (nv) {
            begin = ptr[base + n];
            end = (n == N_ - 1) ? E_ : ptr[base + n + 1];
        }
        f16x8 a0 = {}, a1 = {}, a2 = {}, a3 = {};
        if (nv && q == 0) a0 = *(const f16x8*)&gg[(size_t)n * H_ + mo];  // self-loop
        for (int e = begin; e < end; e += 16) {
            int e0 = e + q;
            int e1 = e0 + 4, e2 = e0 + 8, e3 = e0 + 12;
            if (e0 < end) a0 += *(const f16x8*)&gg[(size_t)cl[e0] * H_ + mo];
            if (e1 < end) a1 += *(const f16x8*)&gg[(size_t)cl[e1] * H_ + mo];
            if (e2 < end) a2 += *(const f16x8*)&gg[(size_t)cl[e2] * H_ + mo];
            if (e3 < end) a3 += *(const f16x8*)&gg[(size_t)cl[e3] * H_ + mo];
        }
        a0 += a1; a2 += a3; a0 += a2;
        union { f16x8 h; int i32[4]; } u;
        u.h = a0;
#pragma unroll
        for (int j = 0; j < 4; ++j) {
            u.i32[j] = addpk(u.i32[j], __shfl(u.i32[j], lane ^ 16, 64));
            u.i32[j] = addpk(u.i32[j], __shfl(u.i32[j], lane ^ 32, 64));
        }
        resv[i] = u.h;   // every lane now holds the full sum for its m-slice
    }

    // epilogue: lane handles node n0+(lane>>4), columns mo..mo+7
    int sel = lane >> 4;
    f16x8 r = resv[0];
    if (sel == 1) r = resv[1];
    if (sel == 2) r = resv[2];
    if (sel == 3) r = resv[3];
    if (epv) {
        f16x8 o;
#pragma unroll
        for (int j = 0; j < 8; ++j) {
            float bj = (j < 4) ? ((const float*)&b4a)[j] : ((const float*)&b4b)[j - 4];
            o[j] = (f16)fast_tanh(dn * (float)r[j] + bj);
        }
        *(f16x8*)&out[((size_t)base + epn) * H_ + mo] = o;  // contiguous 1 KB wave store
    }
}

// ---------------- node-sum: z[t][c] = sum_n h[t][n][c] ----------------
__global__ __launch_bounds__(256) void k_reduce(const f16* __restrict__ h, float* __restrict__ z) {
    int t = blockIdx.x, seg = blockIdx.y;
    int tid = threadIdx.x;
    int rg = tid >> 5;
    int c = (tid & 31) * 4;
    const f16* p = h + (size_t)t * N_ * H_;
    float4 acc = make_float4(0.f, 0.f, 0.f, 0.f);
    int n0 = seg * 500;
    for (int n = n0 + rg; n < n0 + 500; n += 8) {
        f16x4 v = *(const f16x4*)&p[(size_t)n * H_ + c];
        acc.x += (float)v[0]; acc.y += (float)v[1]; acc.z += (float)v[2]; acc.w += (float)v[3];
    }
    __shared__ float4 part[256];
    part[tid] = acc;
    __syncthreads();
    if (rg == 0) {
        float4 s = part[tid];
#pragma unroll
        for (int j = 1; j < 8; ++j) {
            float4 v = part[(j << 5) + tid];
            s.x += v.x; s.y += v.y; s.z += v.z; s.w += v.w;
        }
        atomicAdd(&z[t * H_ + c + 0], s.x);
        atomicAdd(&z[t * H_ + c + 1], s.y);
        atomicAdd(&z[t * H_ + c + 2], s.z);
        atomicAdd(&z[t * H_ + c + 3], s.w);
    }
}

// ---------------- head stage 1: q,k,v ----------------
__global__ __launch_bounds__(128) void k_qkv(const float* __restrict__ z,
                                             const float* __restrict__ Wq, const float* __restrict__ bq,
                                             const float* __restrict__ Wk, const float* __restrict__ bk,
                                             const float* __restrict__ Wv, const float* __restrict__ bv,
                                             float* __restrict__ q, float* __restrict__ k,
                                             float* __restrict__ v) {
    int t = blockIdx.x, c = threadIdx.x;
    __shared__ float zs[128];
    zs[c] = z[t * 128 + c];
    __syncthreads();
    float aq = bq[c], ak = bk[c], av = bv[c];
    for (int kk = 0; kk < 128; ++kk) {
        float zv = zs[kk];
        aq += zv * Wq[(kk << 7) + c];
        ak += zv * Wk[(kk << 7) + c];
        av += zv * Wv[(kk << 7) + c];
    }
    q[t * 128 + c] = aq;
    k[t * 128 + c] = ak;
    v[t * 128 + c] = av;
}

// ---------------- head stage 2 ----------------
__global__ __launch_bounds__(256) void k_attnmid(
    const float* __restrict__ q, const float* __restrict__ k, const float* __restrict__ v,
    const float* __restrict__ Wo, const float* __restrict__ bo,
    const float* __restrict__ g2, const float* __restrict__ beta2,
    const float* __restrict__ Wm1, const float* __restrict__ bm1,
    const float* __restrict__ Wm2, const float* __restrict__ bm2,
    float* __restrict__ xr) {
    int t = blockIdx.x, tid = threadIdx.x;
    __shared__ float Ks[32 * 128], Vs[32 * 128];
    __shared__ float qs[128], sc[8 * 32], xa[128], hid[512], ys[128];
    __shared__ float redA[128], redB[128];

    for (int i = tid; i < 32 * 128; i += 256) { Ks[i] = k[i]; Vs[i] = v[i]; }
    if (tid < 128) qs[tid] = q[t * 128 + tid];
    __syncthreads();

    {
        int h = tid >> 5, s = tid & 31;
        float d = 0.0f;
#pragma unroll
        for (int kk = 0; kk < 16; ++kk)
            d += qs[(h << 4) + kk] * Ks[(s << 7) + (h << 4) + kk];
        sc[tid] = d * 0.25f;
    }
    __syncthreads();
    if (tid < 8) {
        float m = -1e30f;
        for (int s = 0; s < 32; ++s) m = fmaxf(m, sc[(tid << 5) + s]);
        float l = 0.0f;
        for (int s = 0; s < 32; ++s) { float e = __expf(sc[(tid << 5) + s] - m); sc[(tid << 5) + s] = e; l += e; }
        float inv = 1.0f / l;
        for (int s = 0; s < 32; ++s) sc[(tid << 5) + s] *= inv;
    }
    __syncthreads();
    if (tid < 128) {
        int h = tid >> 4;
        float o = 0.0f;
        for (int s = 0; s < 32; ++s) o += sc[(h << 5) + s] * Vs[(s << 7) + tid];
        qs[tid] = o;
    }
    __syncthreads();
    if (tid < 128) {
        float a = bo[tid];
        for (int kk = 0; kk < 128; ++kk) a += qs[kk] * Wo[(kk << 7) + tid];
        xa[tid] = a;
    }
    __syncthreads();
    for (int j = tid; j < 512; j += 256) {
        float a = bm1[j];
        for (int kk = 0; kk < 128; ++kk) a += xa[kk] * Wm1[(kk << 9) + j];
        hid[j] = fmaxf(a, 0.0f);
    }
    __syncthreads();
    if (tid < 128) {
        float a = bm2[tid];
        for (int j = 0; j < 512; ++j) a += hid[j] * Wm2[(j << 7) + tid];
        ys[tid] = xa[tid] + a;
    }
    __syncthreads();
    if (tid < 128) { redA[tid] = ys[tid]; redB[tid] = ys[tid] * ys[tid]; }
    __syncthreads();
    for (int off = 64; off > 0; off >>= 1) {
        if (tid < off) { redA[tid] += redA[tid + off]; redB[tid] += redB[tid + off]; }
        __syncthreads();
    }
    float mu = redA[0] * (1.0f / 128.0f);
    float var = redB[0] * (1.0f / 128.0f) - mu * mu;
    float rs = rsqrtf(var + 1e-5f);
    if (tid < 128) {
        float yv = (ys[tid] - mu) * rs * g2[tid] + beta2[tid];
        xr[t * 128 + tid] = fmaxf(yv, 0.0f);
    }
}

// ---------------- head stage 3 ----------------
__global__ __launch_bounds__(128) void k_final(const float* __restrict__ xr,
                                               const float* __restrict__ Wl,
                                               const float* __restrict__ bl,
                                               float* __restrict__ out) {
    int tid = threadIdx.x;
    __shared__ float pooled[128];
    float s = 0.0f;
    for (int t = 0; t < 32; ++t) s += xr[t * 128 + tid];
    pooled[tid] = s;
    __syncthreads();
    if (tid < C_) {
        float a = bl[tid];
        for (int kk = 0; kk < 128; ++kk) a += pooled[kk] * Wl[kk * C_ + tid];
        out[tid] = a;
    }
}

extern "C" void kernel_launch(void* const* d_in, const int* in_sizes, int n_in,
                              void* d_out, int out_size, void* d_ws, size_t ws_size,
                              hipStream_t stream) {
    const float* x  = (const float*)d_in[0];
    const int*   ei = (const int*)d_in[1];
    const float* W0 = (const float*)d_in[2];  const float* b0 = (const float*)d_in[3];
    const float* W1 = (const float*)d_in[4];  const float* b1 = (const float*)d_in[5];
    const float* W2 = (const float*)d_in[6];  const float* b2 = (const float*)d_in[7];
    const float* Wq = (const float*)d_in[8];  const float* bq = (const float*)d_in[9];
    const float* Wk = (const float*)d_in[10]; const float* bk = (const float*)d_in[11];
    const float* Wv = (const float*)d_in[12]; const float* bv = (const float*)d_in[13];
    const float* Wo = (const float*)d_in[14]; const float* bo = (const float*)d_in[15];
    const float* g2 = (const float*)d_in[16]; const float* beta2 = (const float*)d_in[17];
    const float* Wm1 = (const float*)d_in[18]; const float* bm1 = (const float*)d_in[19];
    const float* Wm2 = (const float*)d_in[20]; const float* bm2 = (const float*)d_in[21];
    const float* Wl = (const float*)d_in[22]; const float* bl = (const float*)d_in[23];
    float* outp = (float*)d_out;

    const size_t BIG = (size_t)T_ * N_ * H_;
    char* ws = (char*)d_ws;
    float*    dinv = (float*)(ws);
    int*      ptr  = (int*)(ws + 640000);
    uint16_t* col  = (uint16_t*)(ws + 1280000);
    f16*      Wt   = (f16*)(ws + 6400000);
    f16*      P16  = (f16*)(ws + 6498304);
    f16*      Q16  = P16 + BIG;
    float*    z    = (float*)(Q16 + BIG);
    float*    zq   = z + 4096;
    float*    zk   = zq + 4096;
    float*    zv   = zk + 4096;
    float*    xr   = zv + 4096;
    int*      part = (int*)P16;   // CSR partials alias P16 (used only before first gemm)

    k_wprep<<<3, 256, 0, stream>>>(W0, W1, W2, Wt);
    k_count<<<NB_ * 32, 256, 0, stream>>>(ei, part);
    k_scan<<<T_, 256, 0, stream>>>(part, ptr, dinv, z);
    k_scatter<<<NB_ * 32, 256, 0, stream>>>(ei, part, col);

    const float* bl_[3] = {b0, b1, b2};
    const int AGGR_BLOCKS = ((N_ + 15) / 16) * 32;   // 4 nodes/wave, 16 nodes/block
    k_gemm<true><<<STRIPS * 32, 256, 0, stream>>>(x, Wt, dinv, P16);
    k_aggr<<<AGGR_BLOCKS, 256, 0, stream>>>(ptr, col, P16, dinv, bl_[0], Q16);
    k_gemm<false><<<STRIPS * 32, 256, 0, stream>>>(Q16, Wt + 16384, dinv, P16);
    k_aggr<<<AGGR_BLOCKS, 256, 0, stream>>>(ptr, col, P16, dinv, bl_[1], Q16);
    k_gemm<false><<<STRIPS * 32, 256, 0, stream>>>(Q16, Wt + 32768, dinv, P16);
    k_aggr<<<AGGR_BLOCKS, 256, 0, stream>>>(ptr, col, P16, dinv, bl_[2], Q16);

    k_reduce<<<dim3(T_, 10), 256, 0, stream>>>(Q16, z);

    k_qkv<<<T_, 128, 0, stream>>>(z, Wq, bq, Wk, bk, Wv, bv, zq, zk, zv);
    k_attnmid<<<T_, 256, 0, stream>>>(zq, zk, zv, Wo, bo, g2, beta2,
                                      Wm1, bm1, Wm2, bm2, xr);
    k_final<<<1, 128, 0, stream>>>(xr, Wl, bl, outp);
}

// Round 2
// 586.452 us; speedup vs baseline: 1.2307x; 1.2307x over previous
//
#include <hip/hip_runtime.h>
#include <cstdint>

#define T_ 32
#define N_ 5000
#define E_ 80000
#define H_ 128
#define HD_ 512
#define C_ 10

typedef _Float16 f16;
typedef f16 f16x8 __attribute__((ext_vector_type(8)));
typedef f16 f16x4 __attribute__((ext_vector_type(4)));
typedef f16 f16x2 __attribute__((ext_vector_type(2)));
typedef float f32x4 __attribute__((ext_vector_type(4)));

#define LDA 136   // padded LDS leading dim in f16
#define NB_ 8     // CSR-build blocks per graph
#define EPS_ (E_ / NB_)  // 10000 edges per block
#define STRIPS 16 // gemm row-strips per graph

__device__ inline int addpk(int a, int b) {
    f16x2 x = __builtin_bit_cast(f16x2, a);
    f16x2 y = __builtin_bit_cast(f16x2, b);
    f16x2 r = x + y;
    return __builtin_bit_cast(int, r);
}

__device__ inline float fast_tanh(float x) {
    return 1.0f - 2.0f / (__expf(2.0f * x) + 1.0f);
}

// ---------------- CSR build, LDS-atomic (no global atomics) ----------------
__global__ __launch_bounds__(256) void k_count(const int* __restrict__ ei, int* __restrict__ part) {
    __shared__ int cnt[N_];
    int blk = blockIdx.x;
    int t = blk & 31, seg = blk >> 5;
    int tid = threadIdx.x;
    for (int i = tid; i < N_; i += 256) cnt[i] = 0;
    __syncthreads();
    const int* dst = ei + (size_t)t * 2 * E_ + E_ + seg * EPS_;
    for (int e = tid * 4; e < EPS_; e += 1024) {
        int4 d = *(const int4*)&dst[e];
        atomicAdd(&cnt[d.x], 1);
        atomicAdd(&cnt[d.y], 1);
        atomicAdd(&cnt[d.z], 1);
        atomicAdd(&cnt[d.w], 1);
    }
    __syncthreads();
    int* p = part + (t * NB_ + seg) * N_;
    for (int i = tid * 4; i < N_; i += 1024) *(int4*)&p[i] = *(const int4*)&cnt[i];
}

__global__ __launch_bounds__(256) void k_scan(int* __restrict__ part, int* __restrict__ ptr,
                                              float* __restrict__ dinv, float* __restrict__ z) {
    int t = blockIdx.x, tid = threadIdx.x;
    __shared__ int red[256];
    int base = t * N_;
    if (tid < 128) z[t * 128 + tid] = 0.0f;   // folded zinit
    int* pp = part + t * NB_ * N_;
    int vals[20];
    int sum = 0;
#pragma unroll
    for (int j = 0; j < 20; ++j) {
        int i = tid * 20 + j;
        int c = 0;
        if (i < N_) {
#pragma unroll
            for (int s = 0; s < NB_; ++s) c += pp[s * N_ + i];
            dinv[base + i] = rsqrtf((float)(c + 1));  // +1 self-loop
        }
        vals[j] = sum;
        sum += c;
    }
    red[tid] = sum;
    __syncthreads();
    for (int off = 1; off < 256; off <<= 1) {
        int v = (tid >= off) ? red[tid - off] : 0;
        __syncthreads();
        red[tid] += v;
        __syncthreads();
    }
    int prev = (tid > 0) ? red[tid - 1] : 0;
#pragma unroll
    for (int j = 0; j < 20; ++j) {
        int i = tid * 20 + j;
        if (i < N_) {
            int start = prev + vals[j];
            ptr[base + i] = start;
            int run = start;
#pragma unroll
            for (int s = 0; s < NB_; ++s) {
                int c = pp[s * N_ + i];
                pp[s * N_ + i] = run;
                run += c;
            }
        }
    }
}

__global__ __launch_bounds__(256) void k_scatter(const int* __restrict__ ei,
                                                 const int* __restrict__ part,
                                                 uint16_t* __restrict__ col) {
    __shared__ int cur[N_];
    int blk = blockIdx.x;
    int t = blk & 31, seg = blk >> 5;
    int tid = threadIdx.x;
    const int* off = part + (t * NB_ + seg) * N_;
    for (int i = tid * 4; i < N_; i += 1024) *(int4*)&cur[i] = *(const int4*)&off[i];
    __syncthreads();
    const int* src = ei + (size_t)t * 2 * E_ + seg * EPS_;
    const int* dst = src + E_;
    uint16_t* cl = col + (size_t)t * E_;
    for (int e = tid * 4; e < EPS_; e += 1024) {
        int4 s4 = *(const int4*)&src[e];
        int4 d4 = *(const int4*)&dst[e];
        cl[atomicAdd(&cur[d4.x], 1)] = (uint16_t)s4.x;
        cl[atomicAdd(&cur[d4.y], 1)] = (uint16_t)s4.y;
        cl[atomicAdd(&cur[d4.z], 1)] = (uint16_t)s4.z;
        cl[atomicAdd(&cur[d4.w], 1)] = (uint16_t)s4.w;
    }
}

// ---------------- weight prep: Wt[l][c][k] = (f16)W_l[k][c] ----------------
__global__ __launch_bounds__(256) void k_wprep(const float* __restrict__ W0,
                                               const float* __restrict__ W1,
                                               const float* __restrict__ W2,
                                               f16* __restrict__ Wt) {
    const float* W = (blockIdx.x == 0) ? W0 : (blockIdx.x == 1) ? W1 : W2;
    f16* dst = Wt + blockIdx.x * 16384;
    for (int idx = threadIdx.x; idx < 16384; idx += 256) {
        int c = idx >> 7, k = idx & 127;
        dst[idx] = (f16)W[k * 128 + c];
    }
}

// ---------------- MFMA GEMM v3: W staged once, loop over row tiles ----------------
template <bool F32IN>
__global__ __launch_bounds__(256) void k_gemm(const void* __restrict__ in_,
                                              const f16* __restrict__ Wt,  // [c][k]
                                              const float* __restrict__ dinv,
                                              f16* __restrict__ g) {
    __shared__ f16 Ws[128 * LDA];
    __shared__ f16 As[64 * LDA];
    int b = blockIdx.x;
    int t = b & 31;
    int strip = b >> 5;
    int tid = threadIdx.x;

    // stage Wt -> Ws ONCE (first barrier is inside the tile loop)
    {
        int c = tid >> 1, hf = tid & 1;
        const f16* src = Wt + c * 128 + hf * 64;
        f16* dst = Ws + c * LDA + hf * 64;
#pragma unroll
        for (int j = 0; j < 8; ++j) *(f16x8*)&dst[j * 8] = *(const f16x8*)&src[j * 8];
    }

    int w = tid >> 6, lane = tid & 63;
    int m = lane & 15, q = lane >> 4;
    int rw = w * 16;
    int sr = tid >> 2, skq = (tid & 3) * 32;   // staging row / k-quarter

    for (int tile = strip; tile < 79; tile += STRIPS) {
        int r0 = tile * 64;
        // stage A
        {
            bool valid = (r0 + sr) < N_;
            f16* dst = As + sr * LDA + skq;
            if (F32IN) {
                const float* src = (const float*)in_ + ((size_t)(t * N_ + r0 + sr)) * H_ + skq;
#pragma unroll
                for (int j = 0; j < 8; ++j) {
                    float4 v = valid ? *(const float4*)&src[j * 4] : make_float4(0.f, 0.f, 0.f, 0.f);
                    dst[j * 4 + 0] = (f16)v.x;
                    dst[j * 4 + 1] = (f16)v.y;
                    dst[j * 4 + 2] = (f16)v.z;
                    dst[j * 4 + 3] = (f16)v.w;
                }
            } else {
                const f16* src = (const f16*)in_ + ((size_t)(t * N_ + r0 + sr)) * H_ + skq;
#pragma unroll
                for (int j = 0; j < 4; ++j) {
                    f16x8 v = {};
                    if (valid) v = *(const f16x8*)&src[j * 8];
                    *(f16x8*)&dst[j * 8] = v;
                }
            }
        }
        __syncthreads();  // A (and Ws on first iter) visible

        f32x4 acc[8];
#pragma unroll
        for (int n = 0; n < 8; ++n) acc[n] = (f32x4){0.f, 0.f, 0.f, 0.f};
#pragma unroll
        for (int kb = 0; kb < 4; ++kb) {
            f16x8 aF = *(const f16x8*)&As[(rw + m) * LDA + kb * 32 + q * 8];
#pragma unroll
            for (int n = 0; n < 8; ++n) {
                f16x8 bF = *(const f16x8*)&Ws[(n * 16 + m) * LDA + kb * 32 + q * 8];
                acc[n] = __builtin_amdgcn_mfma_f32_16x16x32_f16(aF, bF, acc[n], 0, 0, 0);
            }
        }
        __syncthreads();  // done reading As; reuse for epilogue

#pragma unroll
        for (int i = 0; i < 4; ++i) {
            int rr = rw + q * 4 + i;
            int gr = r0 + rr;
            float d = dinv[t * N_ + (gr < N_ ? gr : N_ - 1)];
#pragma unroll
            for (int n = 0; n < 8; ++n)
                As[rr * LDA + n * 16 + m] = (f16)(acc[n][i] * d);
        }
        __syncthreads();
        if (r0 + sr < N_) {
            f16* dst = g + ((size_t)(t * N_ + r0 + sr)) * H_ + skq;
            const f16* src = As + sr * LDA + skq;
#pragma unroll
            for (int j = 0; j < 4; ++j) *(f16x8*)&dst[j * 8] = *(const f16x8*)&src[j * 8];
        }
        __syncthreads();  // As free for next tile's staging
    }
}

// ---------------- CSR gather v3: one node per 16-lane GROUP, zero shuffles ----------------
// Group q (16 lanes, m=0..15) owns node n0+q; its lanes cover the full 128-col row
// (8 cols each), so the group's accumulators ARE the final row slice -- no cross-lane
// reduction at all. 8 independent accumulator chains -> 8 row-gathers in flight per
// group (32/wave). CSR bounds for all 4 nodes come from one int4 load. col-index
// loads are clamped (always-valid) so gathers issue unconditionally; only the adds
// are predicated. No LDS, no __syncthreads, no arrays (named regs only -- a prior
// version's resv[4] array was demoted to LDS by PromoteAlloca: 16KB/block + 4M bank
// conflicts). Epilogue: one contiguous 1KB wave store (4 consecutive rows).
__global__ __launch_bounds__(256) void k_aggr(const int* __restrict__ ptr,
                                              const uint16_t* __restrict__ col,
                                              const f16* __restrict__ g,
                                              const float* __restrict__ dinv,
                                              const float* __restrict__ b,
                                              f16* __restrict__ out) {
    int blk = blockIdx.x;
    int t = blk & 31;            // graph (keeps t%8 == blk%8 XCD affinity)
    int nb = blk >> 5;           // 16-node block
    int w = threadIdx.x >> 6;
    int lane = threadIdx.x & 63;
    int q = lane >> 4, m = lane & 15;
    int n0 = nb * 16 + w * 4;    // this wave's first node (4-aligned; N_%4==0 so
    if (n0 >= N_) return;        //  an active wave always has 4 valid nodes)
    int base = t * N_;
    const f16* gg = g + (size_t)base * H_;
    const uint16_t* cl = col + (size_t)t * E_;
    int mo = m * 8;
    int n = n0 + q;              // this group's node

    // CSR bounds for the wave's 4 nodes: one aligned int4 + one scalar
    int4 p4 = *(const int4*)&ptr[base + n0];
    int pend = (n0 + 4 < N_) ? ptr[base + n0 + 4] : E_;
    int begin = (q == 0) ? p4.x : (q == 1) ? p4.y : (q == 2) ? p4.z : p4.w;
    int end   = (q == 0) ? p4.y : (q == 1) ? p4.z : (q == 2) ? p4.w : pend;

    // epilogue operands hoisted (overlap with gathers)
    float dn = dinv[base + n];
    float4 b4a = *(const float4*)&b[mo];
    float4 b4b = *(const float4*)&b[mo + 4];

    f16x8 a0 = *(const f16x8*)&gg[(size_t)n * H_ + mo];  // self-loop
    f16x8 a1 = {}, a2 = {}, a3 = {}, a4 = {}, a5 = {}, a6 = {}, a7 = {};
    int endm1 = end - 1;
    for (int e = begin; e < end; e += 8) {
        // clamped col-index loads: always valid address/index, maybe duplicated
        int e1 = e + 1 <= endm1 ? e + 1 : endm1;
        int e2 = e + 2 <= endm1 ? e + 2 : endm1;
        int e3 = e + 3 <= endm1 ? e + 3 : endm1;
        int e4 = e + 4 <= endm1 ? e + 4 : endm1;
        int e5 = e + 5 <= endm1 ? e + 5 : endm1;
        int e6 = e + 6 <= endm1 ? e + 6 : endm1;
        int e7 = e + 7 <= endm1 ? e + 7 : endm1;
        int i0 = cl[e];
        int i1 = cl[e1]; int i2 = cl[e2]; int i3 = cl[e3];
        int i4 = cl[e4]; int i5 = cl[e5]; int i6 = cl[e6]; int i7 = cl[e7];
        f16x8 v0 = *(const f16x8*)&gg[(size_t)i0 * H_ + mo];
        f16x8 v1 = *(const f16x8*)&gg[(size_t)i1 * H_ + mo];
        f16x8 v2 = *(const f16x8*)&gg[(size_t)i2 * H_ + mo];
        f16x8 v3 = *(const f16x8*)&gg[(size_t)i3 * H_ + mo];
        f16x8 v4 = *(const f16x8*)&gg[(size_t)i4 * H_ + mo];
        f16x8 v5 = *(const f16x8*)&gg[(size_t)i5 * H_ + mo];
        f16x8 v6 = *(const f16x8*)&gg[(size_t)i6 * H_ + mo];
        f16x8 v7 = *(const f16x8*)&gg[(size_t)i7 * H_ + mo];
        a0 += v0;
        if (e + 1 < end) a1 += v1;
        if (e + 2 < end) a2 += v2;
        if (e + 3 < end) a3 += v3;
        if (e + 4 < end) a4 += v4;
        if (e + 5 < end) a5 += v5;
        if (e + 6 < end) a6 += v6;
        if (e + 7 < end) a7 += v7;
    }
    a0 += a1; a2 += a3; a4 += a5; a6 += a7;
    a0 += a2; a4 += a6;
    a0 += a4;

    f16x8 o;
#pragma unroll
    for (int j = 0; j < 8; ++j) {
        float bj = (j < 4) ? ((const float*)&b4a)[j] : ((const float*)&b4b)[j - 4];
        o[j] = (f16)fast_tanh(dn * (float)a0[j] + bj);
    }
    *(f16x8*)&out[((size_t)base + n) * H_ + mo] = o;  // contiguous 1 KB wave store
}

// ---------------- node-sum: z[t][c] = sum_n h[t][n][c] ----------------
__global__ __launch_bounds__(256) void k_reduce(const f16* __restrict__ h, float* __restrict__ z) {
    int t = blockIdx.x, seg = blockIdx.y;
    int tid = threadIdx.x;
    int rg = tid >> 5;
    int c = (tid & 31) * 4;
    const f16* p = h + (size_t)t * N_ * H_;
    float4 acc = make_float4(0.f, 0.f, 0.f, 0.f);
    int n0 = seg * 500;
    for (int n = n0 + rg; n < n0 + 500; n += 8) {
        f16x4 v = *(const f16x4*)&p[(size_t)n * H_ + c];
        acc.x += (float)v[0]; acc.y += (float)v[1]; acc.z += (float)v[2]; acc.w += (float)v[3];
    }
    __shared__ float4 part[256];
    part[tid] = acc;
    __syncthreads();
    if (rg == 0) {
        float4 s = part[tid];
#pragma unroll
        for (int j = 1; j < 8; ++j) {
            float4 v = part[(j << 5) + tid];
            s.x += v.x; s.y += v.y; s.z += v.z; s.w += v.w;
        }
        atomicAdd(&z[t * H_ + c + 0], s.x);
        atomicAdd(&z[t * H_ + c + 1], s.y);
        atomicAdd(&z[t * H_ + c + 2], s.z);
        atomicAdd(&z[t * H_ + c + 3], s.w);
    }
}

// ---------------- head stage 1: q,k,v ----------------
__global__ __launch_bounds__(128) void k_qkv(const float* __restrict__ z,
                                             const float* __restrict__ Wq, const float* __restrict__ bq,
                                             const float* __restrict__ Wk, const float* __restrict__ bk,
                                             const float* __restrict__ Wv, const float* __restrict__ bv,
                                             float* __restrict__ q, float* __restrict__ k,
                                             float* __restrict__ v) {
    int t = blockIdx.x, c = threadIdx.x;
    __shared__ float zs[128];
    zs[c] = z[t * 128 + c];
    __syncthreads();
    float aq = bq[c], ak = bk[c], av = bv[c];
    for (int kk = 0; kk < 128; ++kk) {
        float zv = zs[kk];
        aq += zv * Wq[(kk << 7) + c];
        ak += zv * Wk[(kk << 7) + c];
        av += zv * Wv[(kk << 7) + c];
    }
    q[t * 128 + c] = aq;
    k[t * 128 + c] = ak;
    v[t * 128 + c] = av;
}

// ---------------- head stage 2 ----------------
__global__ __launch_bounds__(256) void k_attnmid(
    const float* __restrict__ q, const float* __restrict__ k, const float* __restrict__ v,
    const float* __restrict__ Wo, const float* __restrict__ bo,
    const float* __restrict__ g2, const float* __restrict__ beta2,
    const float* __restrict__ Wm1, const float* __restrict__ bm1,
    const float* __restrict__ Wm2, const float* __restrict__ bm2,
    float* __restrict__ xr) {
    int t = blockIdx.x, tid = threadIdx.x;
    __shared__ float Ks[32 * 128], Vs[32 * 128];
    __shared__ float qs[128], sc[8 * 32], xa[128], hid[512], ys[128];
    __shared__ float redA[128], redB[128];

    for (int i = tid; i < 32 * 128; i += 256) { Ks[i] = k[i]; Vs[i] = v[i]; }
    if (tid < 128) qs[tid] = q[t * 128 + tid];
    __syncthreads();

    {
        int h = tid >> 5, s = tid & 31;
        float d = 0.0f;
#pragma unroll
        for (int kk = 0; kk < 16; ++kk)
            d += qs[(h << 4) + kk] * Ks[(s << 7) + (h << 4) + kk];
        sc[tid] = d * 0.25f;
    }
    __syncthreads();
    if (tid < 8) {
        float m = -1e30f;
        for (int s = 0; s < 32; ++s) m = fmaxf(m, sc[(tid << 5) + s]);
        float l = 0.0f;
        for (int s = 0; s < 32; ++s) { float e = __expf(sc[(tid << 5) + s] - m); sc[(tid << 5) + s] = e; l += e; }
        float inv = 1.0f / l;
        for (int s = 0; s < 32; ++s) sc[(tid << 5) + s] *= inv;
    }
    __syncthreads();
    if (tid < 128) {
        int h = tid >> 4;
        float o = 0.0f;
        for (int s = 0; s < 32; ++s) o += sc[(h << 5) + s] * Vs[(s << 7) + tid];
        qs[tid] = o;
    }
    __syncthreads();
    if (tid < 128) {
        float a = bo[tid];
        for (int kk = 0; kk < 128; ++kk) a += qs[kk] * Wo[(kk << 7) + tid];
        xa[tid] = a;
    }
    __syncthreads();
    for (int j = tid; j < 512; j += 256) {
        float a = bm1[j];
        for (int kk = 0; kk < 128; ++kk) a += xa[kk] * Wm1[(kk << 9) + j];
        hid[j] = fmaxf(a, 0.0f);
    }
    __syncthreads();
    if (tid < 128) {
        float a = bm2[tid];
        for (int j = 0; j < 512; ++j) a += hid[j] * Wm2[(j << 7) + tid];
        ys[tid] = xa[tid] + a;
    }
    __syncthreads();
    if (tid < 128) { redA[tid] = ys[tid]; redB[tid] = ys[tid] * ys[tid]; }
    __syncthreads();
    for (int off = 64; off > 0; off >>= 1) {
        if (tid < off) { redA[tid] += redA[tid + off]; redB[tid] += redB[tid + off]; }
        __syncthreads();
    }
    float mu = redA[0] * (1.0f / 128.0f);
    float var = redB[0] * (1.0f / 128.0f) - mu * mu;
    float rs = rsqrtf(var + 1e-5f);
    if (tid < 128) {
        float yv = (ys[tid] - mu) * rs * g2[tid] + beta2[tid];
        xr[t * 128 + tid] = fmaxf(yv, 0.0f);
    }
}

// ---------------- head stage 3 ----------------
__global__ __launch_bounds__(128) void k_final(const float* __restrict__ xr,
                                               const float* __restrict__ Wl,
                                               const float* __restrict__ bl,
                                               float* __restrict__ out) {
    int tid = threadIdx.x;
    __shared__ float pooled[128];
    float s = 0.0f;
    for (int t = 0; t < 32; ++t) s += xr[t * 128 + tid];
    pooled[tid] = s;
    __syncthreads();
    if (tid < C_) {
        float a = bl[tid];
        for (int kk = 0; kk < 128; ++kk) a += pooled[kk] * Wl[kk * C_ + tid];
        out[tid] = a;
    }
}

extern "C" void kernel_launch(void* const* d_in, const int* in_sizes, int n_in,
                              void* d_out, int out_size, void* d_ws, size_t ws_size,
                              hipStream_t stream) {
    const float* x  = (const float*)d_in[0];
    const int*   ei = (const int*)d_in[1];
    const float* W0 = (const float*)d_in[2];  const float* b0 = (const float*)d_in[3];
    const float* W1 = (const float*)d_in[4];  const float* b1 = (const float*)d_in[5];
    const float* W2 = (const float*)d_in[6];  const float* b2 = (const float*)d_in[7];
    const float* Wq = (const float*)d_in[8];  const float* bq = (const float*)d_in[9];
    const float* Wk = (const float*)d_in[10]; const float* bk = (const float*)d_in[11];
    const float* Wv = (const float*)d_in[12]; const float* bv = (const float*)d_in[13];
    const float* Wo = (const float*)d_in[14]; const float* bo = (const float*)d_in[15];
    const float* g2 = (const float*)d_in[16]; const float* beta2 = (const float*)d_in[17];
    const float* Wm1 = (const float*)d_in[18]; const float* bm1 = (const float*)d_in[19];
    const float* Wm2 = (const float*)d_in[20]; const float* bm2 = (const float*)d_in[21];
    const float* Wl = (const float*)d_in[22]; const float* bl = (const float*)d_in[23];
    float* outp = (float*)d_out;

    const size_t BIG = (size_t)T_ * N_ * H_;
    char* ws = (char*)d_ws;
    float*    dinv = (float*)(ws);
    int*      ptr  = (int*)(ws + 640000);
    uint16_t* col  = (uint16_t*)(ws + 1280000);
    f16*      Wt   = (f16*)(ws + 6400000);
    f16*      P16  = (f16*)(ws + 6498304);
    f16*      Q16  = P16 + BIG;
    float*    z    = (float*)(Q16 + BIG);
    float*    zq   = z + 4096;
    float*    zk   = zq + 4096;
    float*    zv   = zk + 4096;
    float*    xr   = zv + 4096;
    int*      part = (int*)P16;   // CSR partials alias P16 (used only before first gemm)

    k_wprep<<<3, 256, 0, stream>>>(W0, W1, W2, Wt);
    k_count<<<NB_ * 32, 256, 0, stream>>>(ei, part);
    k_scan<<<T_, 256, 0, stream>>>(part, ptr, dinv, z);
    k_scatter<<<NB_ * 32, 256, 0, stream>>>(ei, part, col);

    const float* bl_[3] = {b0, b1, b2};
    const int AGGR_BLOCKS = ((N_ + 15) / 16) * 32;   // 16 nodes/block, 4 nodes/wave
    k_gemm<true><<<STRIPS * 32, 256, 0, stream>>>(x, Wt, dinv, P16);
    k_aggr<<<AGGR_BLOCKS, 256, 0, stream>>>(ptr, col, P16, dinv, bl_[0], Q16);
    k_gemm<false><<<STRIPS * 32, 256, 0, stream>>>(Q16, Wt + 16384, dinv, P16);
    k_aggr<<<AGGR_BLOCKS, 256, 0, stream>>>(ptr, col, P16, dinv, bl_[1], Q16);
    k_gemm<false><<<STRIPS * 32, 256, 0, stream>>>(Q16, Wt + 32768, dinv, P16);
    k_aggr<<<AGGR_BLOCKS, 256, 0, stream>>>(ptr, col, P16, dinv, bl_[2], Q16);

    k_reduce<<<dim3(T_, 10), 256, 0, stream>>>(Q16, z);

    k_qkv<<<T_, 128, 0, stream>>>(z, Wq, bq, Wk, bk, Wv, bv, zq, zk, zv);
    k_attnmid<<<T_, 256, 0, stream>>>(zq, zk, zv, Wo, bo, g2, beta2,
                                      Wm1, bm1, Wm2, bm2, xr);
    k_final<<<1, 128, 0, stream>>>(xr, Wl, bl, outp);
}

// Round 4
// 565.032 us; speedup vs baseline: 1.2774x; 1.0379x over previous
//
#include <hip/hip_runtime.h>
#include <cstdint>

#define T_ 32
#define N_ 5000
#define E_ 80000
#define H_ 128
#define HD_ 512
#define C_ 10

typedef _Float16 f16;
typedef f16 f16x8 __attribute__((ext_vector_type(8)));
typedef f16 f16x4 __attribute__((ext_vector_type(4)));
typedef f16 f16x2 __attribute__((ext_vector_type(2)));
typedef float f32x4 __attribute__((ext_vector_type(4)));

#define LDA 136   // padded LDS leading dim in f16
#define NB_ 8     // CSR-build blocks per graph
#define EPS_ (E_ / NB_)  // 10000 edges per block
#define STRIPS 16 // gemm row-strips per graph
#define NBLK_ 313 // ceil(N_/16) node-blocks per graph (aggr)

__device__ inline int addpk(int a, int b) {
    f16x2 x = __builtin_bit_cast(f16x2, a);
    f16x2 y = __builtin_bit_cast(f16x2, b);
    f16x2 r = x + y;
    return __builtin_bit_cast(int, r);
}

__device__ inline float fast_tanh(float x) {
    return 1.0f - 2.0f / (__expf(2.0f * x) + 1.0f);
}

// ---------------- CSR build, LDS-atomic (no global atomics) ----------------
__global__ __launch_bounds__(256) void k_count(const int* __restrict__ ei, int* __restrict__ part) {
    __shared__ int cnt[N_];
    int blk = blockIdx.x;
    int t = blk & 31, seg = blk >> 5;
    int tid = threadIdx.x;
    for (int i = tid; i < N_; i += 256) cnt[i] = 0;
    __syncthreads();
    const int* dst = ei + (size_t)t * 2 * E_ + E_ + seg * EPS_;
    for (int e = tid * 4; e < EPS_; e += 1024) {
        int4 d = *(const int4*)&dst[e];
        atomicAdd(&cnt[d.x], 1);
        atomicAdd(&cnt[d.y], 1);
        atomicAdd(&cnt[d.z], 1);
        atomicAdd(&cnt[d.w], 1);
    }
    __syncthreads();
    int* p = part + (t * NB_ + seg) * N_;
    for (int i = tid * 4; i < N_; i += 1024) *(int4*)&p[i] = *(const int4*)&cnt[i];
}

__global__ __launch_bounds__(256) void k_scan(int* __restrict__ part, int* __restrict__ ptr,
                                              float* __restrict__ dinv, float* __restrict__ z) {
    int t = blockIdx.x, tid = threadIdx.x;
    __shared__ int red[256];
    int base = t * N_;
    if (tid < 128) z[t * 128 + tid] = 0.0f;   // folded zinit (also the aggr zero-row source)
    int* pp = part + t * NB_ * N_;
    int vals[20];
    int sum = 0;
#pragma unroll
    for (int j = 0; j < 20; ++j) {
        int i = tid * 20 + j;
        int c = 0;
        if (i < N_) {
#pragma unroll
            for (int s = 0; s < NB_; ++s) c += pp[s * N_ + i];
            dinv[base + i] = rsqrtf((float)(c + 1));  // +1 self-loop
        }
        vals[j] = sum;
        sum += c;
    }
    red[tid] = sum;
    __syncthreads();
    for (int off = 1; off < 256; off <<= 1) {
        int v = (tid >= off) ? red[tid - off] : 0;
        __syncthreads();
        red[tid] += v;
        __syncthreads();
    }
    int prev = (tid > 0) ? red[tid - 1] : 0;
#pragma unroll
    for (int j = 0; j < 20; ++j) {
        int i = tid * 20 + j;
        if (i < N_) {
            int start = prev + vals[j];
            ptr[base + i] = start;
            int run = start;
#pragma unroll
            for (int s = 0; s < NB_; ++s) {
                int c = pp[s * N_ + i];
                pp[s * N_ + i] = run;
                run += c;
            }
        }
    }
}

__global__ __launch_bounds__(256) void k_scatter(const int* __restrict__ ei,
                                                 const int* __restrict__ part,
                                                 uint16_t* __restrict__ col) {
    __shared__ int cur[N_];
    int blk = blockIdx.x;
    int t = blk & 31, seg = blk >> 5;
    int tid = threadIdx.x;
    const int* off = part + (t * NB_ + seg) * N_;
    for (int i = tid * 4; i < N_; i += 1024) *(int4*)&cur[i] = *(const int4*)&off[i];
    __syncthreads();
    const int* src = ei + (size_t)t * 2 * E_ + seg * EPS_;
    const int* dst = src + E_;
    uint16_t* cl = col + (size_t)t * E_;
    for (int e = tid * 4; e < EPS_; e += 1024) {
        int4 s4 = *(const int4*)&src[e];
        int4 d4 = *(const int4*)&dst[e];
        cl[atomicAdd(&cur[d4.x], 1)] = (uint16_t)s4.x;
        cl[atomicAdd(&cur[d4.y], 1)] = (uint16_t)s4.y;
        cl[atomicAdd(&cur[d4.z], 1)] = (uint16_t)s4.z;
        cl[atomicAdd(&cur[d4.w], 1)] = (uint16_t)s4.w;
    }
}

// ---------------- weight prep: Wt[l][c][k] = (f16)W_l[k][c] ----------------
__global__ __launch_bounds__(256) void k_wprep(const float* __restrict__ W0,
                                               const float* __restrict__ W1,
                                               const float* __restrict__ W2,
                                               f16* __restrict__ Wt) {
    const float* W = (blockIdx.x == 0) ? W0 : (blockIdx.x == 1) ? W1 : W2;
    f16* dst = Wt + blockIdx.x * 16384;
    for (int idx = threadIdx.x; idx < 16384; idx += 256) {
        int c = idx >> 7, k = idx & 127;
        dst[idx] = (f16)W[k * 128 + c];
    }
}

// ---------------- MFMA GEMM v3: W staged once, loop over row tiles ----------------
template <bool F32IN>
__global__ __launch_bounds__(256) void k_gemm(const void* __restrict__ in_,
                                              const f16* __restrict__ Wt,  // [c][k]
                                              const float* __restrict__ dinv,
                                              f16* __restrict__ g) {
    __shared__ f16 Ws[128 * LDA];
    __shared__ f16 As[64 * LDA];
    int b = blockIdx.x;
    int t = b & 31;
    int strip = b >> 5;
    int tid = threadIdx.x;

    // stage Wt -> Ws ONCE (first barrier is inside the tile loop)
    {
        int c = tid >> 1, hf = tid & 1;
        const f16* src = Wt + c * 128 + hf * 64;
        f16* dst = Ws + c * LDA + hf * 64;
#pragma unroll
        for (int j = 0; j < 8; ++j) *(f16x8*)&dst[j * 8] = *(const f16x8*)&src[j * 8];
    }

    int w = tid >> 6, lane = tid & 63;
    int m = lane & 15, q = lane >> 4;
    int rw = w * 16;
    int sr = tid >> 2, skq = (tid & 3) * 32;   // staging row / k-quarter

    for (int tile = strip; tile < 79; tile += STRIPS) {
        int r0 = tile * 64;
        // stage A
        {
            bool valid = (r0 + sr) < N_;
            f16* dst = As + sr * LDA + skq;
            if (F32IN) {
                const float* src = (const float*)in_ + ((size_t)(t * N_ + r0 + sr)) * H_ + skq;
#pragma unroll
                for (int j = 0; j < 8; ++j) {
                    float4 v = valid ? *(const float4*)&src[j * 4] : make_float4(0.f, 0.f, 0.f, 0.f);
                    dst[j * 4 + 0] = (f16)v.x;
                    dst[j * 4 + 1] = (f16)v.y;
                    dst[j * 4 + 2] = (f16)v.z;
                    dst[j * 4 + 3] = (f16)v.w;
                }
            } else {
                const f16* src = (const f16*)in_ + ((size_t)(t * N_ + r0 + sr)) * H_ + skq;
#pragma unroll
                for (int j = 0; j < 4; ++j) {
                    f16x8 v = {};
                    if (valid) v = *(const f16x8*)&src[j * 8];
                    *(f16x8*)&dst[j * 8] = v;
                }
            }
        }
        __syncthreads();  // A (and Ws on first iter) visible

        f32x4 acc[8];
#pragma unroll
        for (int n = 0; n < 8; ++n) acc[n] = (f32x4){0.f, 0.f, 0.f, 0.f};
#pragma unroll
        for (int kb = 0; kb < 4; ++kb) {
            f16x8 aF = *(const f16x8*)&As[(rw + m) * LDA + kb * 32 + q * 8];
#pragma unroll
            for (int n = 0; n < 8; ++n) {
                f16x8 bF = *(const f16x8*)&Ws[(n * 16 + m) * LDA + kb * 32 + q * 8];
                acc[n] = __builtin_amdgcn_mfma_f32_16x16x32_f16(aF, bF, acc[n], 0, 0, 0);
            }
        }
        __syncthreads();  // done reading As; reuse for epilogue

#pragma unroll
        for (int i = 0; i < 4; ++i) {
            int rr = rw + q * 4 + i;
            int gr = r0 + rr;
            float d = dinv[t * N_ + (gr < N_ ? gr : N_ - 1)];
#pragma unroll
            for (int n = 0; n < 8; ++n)
                As[rr * LDA + n * 16 + m] = (f16)(acc[n][i] * d);
        }
        __syncthreads();
        if (r0 + sr < N_) {
            f16* dst = g + ((size_t)(t * N_ + r0 + sr)) * H_ + skq;
            const f16* src = As + sr * LDA + skq;
#pragma unroll
            for (int j = 0; j < 4; ++j) *(f16x8*)&dst[j * 8] = *(const f16x8*)&src[j * 8];
        }
        __syncthreads();  // As free for next tile's staging
    }
}

// ---------------- CSR gather v4 ----------------
// v3 + two changes:
// (1) Graph-major per-XCD block order: XCD = blk&7 (HW round-robin); the j-th
//     block on an XCD maps to graph x+8*(j/NBLK_), node-block j%NBLK_. One
//     graph's gather set (~2.7MB) stays resident in the 4MB XCD L2 instead of
//     4 graphs interleaved (~11MB thrash). v3 FETCH was 105MB vs 47 compulsory.
// (2) 8-aligned edge chunks: one dwordx4 col load per 8 edges (prefetched one
//     chunk ahead), no index clamping (neighbors' col entries are valid rows),
//     out-of-range lanes redirected via ONE cndmask to a known-zero row (the z
//     buffer: zeroed by k_scan, first written by k_reduce AFTER all aggr calls;
//     it sits exactly 2*BIG f16 after P16 -> row index 320000-5000*t from gg).
//     Adds are unconditional. ~10 VALU + 1.1 VMEM per edge (was ~14 + 2).
__global__ __launch_bounds__(256) void k_aggr(const int* __restrict__ ptr,
                                              const uint16_t* __restrict__ col,
                                              const f16* __restrict__ g,
                                              const float* __restrict__ dinv,
                                              const float* __restrict__ b,
                                              f16* __restrict__ out) {
    int x = blockIdx.x & 7;
    int j = blockIdx.x >> 3;
    int gsel = j / NBLK_;
    int nb = j - gsel * NBLK_;
    int t = x + (gsel << 3);

    int w = threadIdx.x >> 6;
    int lane = threadIdx.x & 63;
    int q = lane >> 4, m = lane & 15;
    int n0 = nb * 16 + w * 4;    // wave's first node (4-aligned)
    if (n0 >= N_) return;        // tail waves (no barriers in this kernel)
    int base = t * N_;
    const f16* gg = g + (size_t)base * H_;
    const uint16_t* cl = col + (size_t)t * E_;
    int n = n0 + q;              // this 16-lane group's node
    unsigned moB = (unsigned)(m * 8);   // lane's 8-col slice (element offset)

    // CSR bounds for the wave's 4 nodes: one aligned int4 + one scalar
    int4 p4 = *(const int4*)&ptr[base + n0];
    int pend = (n0 + 4 < N_) ? ptr[base + n0 + 4] : E_;
    int begin = (q == 0) ? p4.x : (q == 1) ? p4.y : (q == 2) ? p4.z : p4.w;
    int end   = (q == 0) ? p4.y : (q == 1) ? p4.z : (q == 2) ? p4.w : pend;

    // epilogue operands hoisted (overlap with gathers)
    float dn = dinv[base + n];
    float4 b4a = *(const float4*)&b[m * 8];
    float4 b4b = *(const float4*)&b[m * 8 + 4];

    // zero-row index relative to gg (see header comment; layout-coupled!)
    int zidx = 320000 - 5000 * t;

    f16x8 a0 = *(const f16x8*)&gg[((unsigned)n << 7) + moB];  // self-loop row
    f16x8 a1 = {}, a2 = {}, a3 = {}, a4 = {}, a5 = {}, a6 = {}, a7 = {};

    int e0 = begin & ~7;
    int elast = (end - 1) & ~7;          // last chunk start (unused if deg==0)
    unsigned span = (unsigned)(end - begin);
    uint4 cc = *(const uint4*)&cl[e0];   // 16B-aligned; always valid ws memory
    for (int e = e0; e < end; e += 8) {
        int en = e + 8;
        int epf = en < elast ? en : elast;
        uint4 cn = *(const uint4*)&cl[epf];   // prefetch next chunk's cols
        unsigned eb = (unsigned)(e - begin);  // wraps on first chunk; cmp trick ok
        int i0 = (int)(cc.x & 0xFFFFu), i1 = (int)(cc.x >> 16);
        int i2 = (int)(cc.y & 0xFFFFu), i3 = (int)(cc.y >> 16);
        int i4 = (int)(cc.z & 0xFFFFu), i5 = (int)(cc.z >> 16);
        int i6 = (int)(cc.w & 0xFFFFu), i7 = (int)(cc.w >> 16);
        int s0 = (eb + 0 < span) ? i0 : zidx;
        int s1 = (eb + 1 < span) ? i1 : zidx;
        int s2 = (eb + 2 < span) ? i2 : zidx;
        int s3 = (eb + 3 < span) ? i3 : zidx;
        int s4 = (eb + 4 < span) ? i4 : zidx;
        int s5 = (eb + 5 < span) ? i5 : zidx;
        int s6 = (eb + 6 < span) ? i6 : zidx;
        int s7 = (eb + 7 < span) ? i7 : zidx;
        f16x8 v0 = *(const f16x8*)&gg[((unsigned)s0 << 7) + moB];
        f16x8 v1 = *(const f16x8*)&gg[((unsigned)s1 << 7) + moB];
        f16x8 v2 = *(const f16x8*)&gg[((unsigned)s2 << 7) + moB];
        f16x8 v3 = *(const f16x8*)&gg[((unsigned)s3 << 7) + moB];
        f16x8 v4 = *(const f16x8*)&gg[((unsigned)s4 << 7) + moB];
        f16x8 v5 = *(const f16x8*)&gg[((unsigned)s5 << 7) + moB];
        f16x8 v6 = *(const f16x8*)&gg[((unsigned)s6 << 7) + moB];
        f16x8 v7 = *(const f16x8*)&gg[((unsigned)s7 << 7) + moB];
        a0 += v0; a1 += v1; a2 += v2; a3 += v3;
        a4 += v4; a5 += v5; a6 += v6; a7 += v7;
        cc = cn;
    }
    a0 += a1; a2 += a3; a4 += a5; a6 += a7;
    a0 += a2; a4 += a6;
    a0 += a4;

    f16x8 o;
#pragma unroll
    for (int jj = 0; jj < 8; ++jj) {
        float bj = (jj < 4) ? ((const float*)&b4a)[jj] : ((const float*)&b4b)[jj - 4];
        o[jj] = (f16)fast_tanh(dn * (float)a0[jj] + bj);
    }
    *(f16x8*)&out[((size_t)base + n) * H_ + moB] = o;  // contiguous 1 KB wave store
}

// ---------------- node-sum: z[t][c] = sum_n h[t][n][c] ----------------
__global__ __launch_bounds__(256) void k_reduce(const f16* __restrict__ h, float* __restrict__ z) {
    int t = blockIdx.x, seg = blockIdx.y;
    int tid = threadIdx.x;
    int rg = tid >> 5;
    int c = (tid & 31) * 4;
    const f16* p = h + (size_t)t * N_ * H_;
    float4 acc = make_float4(0.f, 0.f, 0.f, 0.f);
    int n0 = seg * 500;
    for (int n = n0 + rg; n < n0 + 500; n += 8) {
        f16x4 v = *(const f16x4*)&p[(size_t)n * H_ + c];
        acc.x += (float)v[0]; acc.y += (float)v[1]; acc.z += (float)v[2]; acc.w += (float)v[3];
    }
    __shared__ float4 part[256];
    part[tid] = acc;
    __syncthreads();
    if (rg == 0) {
        float4 s = part[tid];
#pragma unroll
        for (int j = 1; j < 8; ++j) {
            float4 v = part[(j << 5) + tid];
            s.x += v.x; s.y += v.y; s.z += v.z; s.w += v.w;
        }
        atomicAdd(&z[t * H_ + c + 0], s.x);
        atomicAdd(&z[t * H_ + c + 1], s.y);
        atomicAdd(&z[t * H_ + c + 2], s.z);
        atomicAdd(&z[t * H_ + c + 3], s.w);
    }
}

// ---------------- head stage 1: q,k,v ----------------
__global__ __launch_bounds__(128) void k_qkv(const float* __restrict__ z,
                                             const float* __restrict__ Wq, const float* __restrict__ bq,
                                             const float* __restrict__ Wk, const float* __restrict__ bk,
                                             const float* __restrict__ Wv, const float* __restrict__ bv,
                                             float* __restrict__ q, float* __restrict__ k,
                                             float* __restrict__ v) {
    int t = blockIdx.x, c = threadIdx.x;
    __shared__ float zs[128];
    zs[c] = z[t * 128 + c];
    __syncthreads();
    float aq = bq[c], ak = bk[c], av = bv[c];
    for (int kk = 0; kk < 128; ++kk) {
        float zv = zs[kk];
        aq += zv * Wq[(kk << 7) + c];
        ak += zv * Wk[(kk << 7) + c];
        av += zv * Wv[(kk << 7) + c];
    }
    q[t * 128 + c] = aq;
    k[t * 128 + c] = ak;
    v[t * 128 + c] = av;
}

// ---------------- head stage 2 ----------------
__global__ __launch_bounds__(256) void k_attnmid(
    const float* __restrict__ q, const float* __restrict__ k, const float* __restrict__ v,
    const float* __restrict__ Wo, const float* __restrict__ bo,
    const float* __restrict__ g2, const float* __restrict__ beta2,
    const float* __restrict__ Wm1, const float* __restrict__ bm1,
    const float* __restrict__ Wm2, const float* __restrict__ bm2,
    float* __restrict__ xr) {
    int t = blockIdx.x, tid = threadIdx.x;
    __shared__ float Ks[32 * 128], Vs[32 * 128];
    __shared__ float qs[128], sc[8 * 32], xa[128], hid[512], ys[128];
    __shared__ float redA[128], redB[128];

    for (int i = tid; i < 32 * 128; i += 256) { Ks[i] = k[i]; Vs[i] = v[i]; }
    if (tid < 128) qs[tid] = q[t * 128 + tid];
    __syncthreads();

    {
        int h = tid >> 5, s = tid & 31;
        float d = 0.0f;
#pragma unroll
        for (int kk = 0; kk < 16; ++kk)
            d += qs[(h << 4) + kk] * Ks[(s << 7) + (h << 4) + kk];
        sc[tid] = d * 0.25f;
    }
    __syncthreads();
    if (tid < 8) {
        float m = -1e30f;
        for (int s = 0; s < 32; ++s) m = fmaxf(m, sc[(tid << 5) + s]);
        float l = 0.0f;
        for (int s = 0; s < 32; ++s) { float e = __expf(sc[(tid << 5) + s] - m); sc[(tid << 5) + s] = e; l += e; }
        float inv = 1.0f / l;
        for (int s = 0; s < 32; ++s) sc[(tid << 5) + s] *= inv;
    }
    __syncthreads();
    if (tid < 128) {
        int h = tid >> 4;
        float o = 0.0f;
        for (int s = 0; s < 32; ++s) o += sc[(h << 5) + s] * Vs[(s << 7) + tid];
        qs[tid] = o;
    }
    __syncthreads();
    if (tid < 128) {
        float a = bo[tid];
        for (int kk = 0; kk < 128; ++kk) a += qs[kk] * Wo[(kk << 7) + tid];
        xa[tid] = a;
    }
    __syncthreads();
    for (int j = tid; j < 512; j += 256) {
        float a = bm1[j];
        for (int kk = 0; kk < 128; ++kk) a += xa[kk] * Wm1[(kk << 9) + j];
        hid[j] = fmaxf(a, 0.0f);
    }
    __syncthreads();
    if (tid < 128) {
        float a = bm2[tid];
        for (int j = 0; j < 512; ++j) a += hid[j] * Wm2[(j << 7) + tid];
        ys[tid] = xa[tid] + a;
    }
    __syncthreads();
    if (tid < 128) { redA[tid] = ys[tid]; redB[tid] = ys[tid] * ys[tid]; }
    __syncthreads();
    for (int off = 64; off > 0; off >>= 1) {
        if (tid < off) { redA[tid] += redA[tid + off]; redB[tid] += redB[tid + off]; }
        __syncthreads();
    }
    float mu = redA[0] * (1.0f / 128.0f);
    float var = redB[0] * (1.0f / 128.0f) - mu * mu;
    float rs = rsqrtf(var + 1e-5f);
    if (tid < 128) {
        float yv = (ys[tid] - mu) * rs * g2[tid] + beta2[tid];
        xr[t * 128 + tid] = fmaxf(yv, 0.0f);
    }
}

// ---------------- head stage 3 ----------------
__global__ __launch_bounds__(128) void k_final(const float* __restrict__ xr,
                                               const float* __restrict__ Wl,
                                               const float* __restrict__ bl,
                                               float* __restrict__ out) {
    int tid = threadIdx.x;
    __shared__ float pooled[128];
    float s = 0.0f;
    for (int t = 0; t < 32; ++t) s += xr[t * 128 + tid];
    pooled[tid] = s;
    __syncthreads();
    if (tid < C_) {
        float a = bl[tid];
        for (int kk = 0; kk < 128; ++kk) a += pooled[kk] * Wl[kk * C_ + tid];
        out[tid] = a;
    }
}

extern "C" void kernel_launch(void* const* d_in, const int* in_sizes, int n_in,
                              void* d_out, int out_size, void* d_ws, size_t ws_size,
                              hipStream_t stream) {
    const float* x  = (const float*)d_in[0];
    const int*   ei = (const int*)d_in[1];
    const float* W0 = (const float*)d_in[2];  const float* b0 = (const float*)d_in[3];
    const float* W1 = (const float*)d_in[4];  const float* b1 = (const float*)d_in[5];
    const float* W2 = (const float*)d_in[6];  const float* b2 = (const float*)d_in[7];
    const float* Wq = (const float*)d_in[8];  const float* bq = (const float*)d_in[9];
    const float* Wk = (const float*)d_in[10]; const float* bk = (const float*)d_in[11];
    const float* Wv = (const float*)d_in[12]; const float* bv = (const float*)d_in[13];
    const float* Wo = (const float*)d_in[14]; const float* bo = (const float*)d_in[15];
    const float* g2 = (const float*)d_in[16]; const float* beta2 = (const float*)d_in[17];
    const float* Wm1 = (const float*)d_in[18]; const float* bm1 = (const float*)d_in[19];
    const float* Wm2 = (const float*)d_in[20]; const float* bm2 = (const float*)d_in[21];
    const float* Wl = (const float*)d_in[22]; const float* bl = (const float*)d_in[23];
    float* outp = (float*)d_out;

    const size_t BIG = (size_t)T_ * N_ * H_;
    char* ws = (char*)d_ws;
    float*    dinv = (float*)(ws);
    int*      ptr  = (int*)(ws + 640000);
    uint16_t* col  = (uint16_t*)(ws + 1280000);
    f16*      Wt   = (f16*)(ws + 6400000);
    f16*      P16  = (f16*)(ws + 6498304);
    f16*      Q16  = P16 + BIG;
    float*    z    = (float*)(Q16 + BIG);   // NOTE: k_aggr's zero-row aliases z[0..63]
    float*    zq   = z + 4096;
    float*    zk   = zq + 4096;
    float*    zv   = zk + 4096;
    float*    xr   = zv + 4096;
    int*      part = (int*)P16;   // CSR partials alias P16 (used only before first gemm)

    k_wprep<<<3, 256, 0, stream>>>(W0, W1, W2, Wt);
    k_count<<<NB_ * 32, 256, 0, stream>>>(ei, part);
    k_scan<<<T_, 256, 0, stream>>>(part, ptr, dinv, z);
    k_scatter<<<NB_ * 32, 256, 0, stream>>>(ei, part, col);

    const float* bl_[3] = {b0, b1, b2};
    const int AGGR_BLOCKS = NBLK_ * 32;   // 16 nodes/block, 4 nodes/wave
    k_gemm<true><<<STRIPS * 32, 256, 0, stream>>>(x, Wt, dinv, P16);
    k_aggr<<<AGGR_BLOCKS, 256, 0, stream>>>(ptr, col, P16, dinv, bl_[0], Q16);
    k_gemm<false><<<STRIPS * 32, 256, 0, stream>>>(Q16, Wt + 16384, dinv, P16);
    k_aggr<<<AGGR_BLOCKS, 256, 0, stream>>>(ptr, col, P16, dinv, bl_[1], Q16);
    k_gemm<false><<<STRIPS * 32, 256, 0, stream>>>(Q16, Wt + 32768, dinv, P16);
    k_aggr<<<AGGR_BLOCKS, 256, 0, stream>>>(ptr, col, P16, dinv, bl_[2], Q16);

    k_reduce<<<dim3(T_, 10), 256, 0, stream>>>(Q16, z);

    k_qkv<<<T_, 128, 0, stream>>>(z, Wq, bq, Wk, bk, Wv, bv, zq, zk, zv);
    k_attnmid<<<T_, 256, 0, stream>>>(zq, zk, zv, Wo, bo, g2, beta2,
                                      Wm1, bm1, Wm2, bm2, xr);
    k_final<<<1, 128, 0, stream>>>(xr, Wl, bl, outp);
}

// Round 5
// 521.223 us; speedup vs baseline: 1.3847x; 1.0841x over previous
//
#include <hip/hip_runtime.h>
#include <cstdint>

#define T_ 32
#define N_ 5000
#define E_ 80000
#define H_ 128
#define HD_ 512
#define C_ 10

typedef _Float16 f16;
typedef f16 f16x8 __attribute__((ext_vector_type(8)));
typedef f16 f16x4 __attribute__((ext_vector_type(4)));
typedef f16 f16x2 __attribute__((ext_vector_type(2)));
typedef float f32x4 __attribute__((ext_vector_type(4)));

#define LDA 136   // padded LDS leading dim in f16
#define NB_ 8     // CSR-build blocks per graph
#define EPS_ (E_ / NB_)  // 10000 edges per block
#define STRIPS 16 // gemm row-strips per graph
#define NBLK_ 313 // ceil(N_/16) node-blocks per graph (aggr)

__device__ inline int addpk(int a, int b) {
    f16x2 x = __builtin_bit_cast(f16x2, a);
    f16x2 y = __builtin_bit_cast(f16x2, b);
    f16x2 r = x + y;
    return __builtin_bit_cast(int, r);
}

__device__ inline float fast_tanh(float x) {
    return 1.0f - 2.0f / (__expf(2.0f * x) + 1.0f);
}

// ---------------- CSR build, LDS-atomic (no global atomics) ----------------
__global__ __launch_bounds__(256) void k_count(const int* __restrict__ ei, int* __restrict__ part) {
    __shared__ int cnt[N_];
    int blk = blockIdx.x;
    int t = blk & 31, seg = blk >> 5;
    int tid = threadIdx.x;
    for (int i = tid; i < N_; i += 256) cnt[i] = 0;
    __syncthreads();
    const int* dst = ei + (size_t)t * 2 * E_ + E_ + seg * EPS_;
    for (int e = tid * 4; e < EPS_; e += 1024) {
        int4 d = *(const int4*)&dst[e];
        atomicAdd(&cnt[d.x], 1);
        atomicAdd(&cnt[d.y], 1);
        atomicAdd(&cnt[d.z], 1);
        atomicAdd(&cnt[d.w], 1);
    }
    __syncthreads();
    int* p = part + (t * NB_ + seg) * N_;
    for (int i = tid * 4; i < N_; i += 1024) *(int4*)&p[i] = *(const int4*)&cnt[i];
}

// ---------------- scan v2: coalesced degree/fixup phases, LDS-staged scan ----------------
// v4's k_scan was 59µs at 0.4% VALU / 1.9% HBM: blocked ownership (tid*20..+19)
// made every global access uncoalesced (80B lane stride) and latency-serialized.
// Now: Phase A computes degrees with stride-256 COALESCED loads into LDS;
// Phase B scans blocked runs out of LDS (no global latency in the chain);
// Phase C re-walks pp with coalesced loads/stores for the per-segment fixup.
__global__ __launch_bounds__(256) void k_scan(int* __restrict__ part, int* __restrict__ ptr,
                                              float* __restrict__ dinv, float* __restrict__ z) {
    __shared__ int cnt[N_];      // degree, then start offset
    __shared__ int red[256];
    int t = blockIdx.x, tid = threadIdx.x;
    int base = t * N_;
    if (tid < 128) z[t * 128 + tid] = 0.0f;   // folded zinit (also the aggr zero-row source)
    int* pp = part + t * NB_ * N_;

    // Phase A: coalesced degree computation
    for (int i = tid; i < N_; i += 256) {
        int c = 0;
#pragma unroll
        for (int s = 0; s < NB_; ++s) c += pp[s * N_ + i];
        cnt[i] = c;
        dinv[base + i] = rsqrtf((float)(c + 1));  // +1 self-loop
    }
    __syncthreads();

    // Phase B: block scan over blocked 20-element runs (LDS source)
    int vals[20];
    int sum = 0;
#pragma unroll
    for (int j = 0; j < 20; ++j) {
        int i = tid * 20 + j;
        int c = (i < N_) ? cnt[i] : 0;
        vals[j] = sum;
        sum += c;
    }
    red[tid] = sum;
    __syncthreads();
    for (int off = 1; off < 256; off <<= 1) {
        int v = (tid >= off) ? red[tid - off] : 0;
        __syncthreads();
        red[tid] += v;
        __syncthreads();
    }
    int prev = (tid > 0) ? red[tid - 1] : 0;
#pragma unroll
    for (int j = 0; j < 20; ++j) {
        int i = tid * 20 + j;
        if (i < N_) cnt[i] = prev + vals[j];   // overwrite degree with start offset
    }
    __syncthreads();

    // Phase C: coalesced ptr write + per-segment running-offset fixup
    for (int i = tid; i < N_; i += 256) {
        int run = cnt[i];
        ptr[base + i] = run;
#pragma unroll
        for (int s = 0; s < NB_; ++s) {
            int c = pp[s * N_ + i];
            pp[s * N_ + i] = run;
            run += c;
        }
    }
}

__global__ __launch_bounds__(256) void k_scatter(const int* __restrict__ ei,
                                                 const int* __restrict__ part,
                                                 uint16_t* __restrict__ col) {
    __shared__ int cur[N_];
    int blk = blockIdx.x;
    int t = blk & 31, seg = blk >> 5;
    int tid = threadIdx.x;
    const int* off = part + (t * NB_ + seg) * N_;
    for (int i = tid * 4; i < N_; i += 1024) *(int4*)&cur[i] = *(const int4*)&off[i];
    __syncthreads();
    const int* src = ei + (size_t)t * 2 * E_ + seg * EPS_;
    const int* dst = src + E_;
    uint16_t* cl = col + (size_t)t * E_;
    for (int e = tid * 4; e < EPS_; e += 1024) {
        int4 s4 = *(const int4*)&src[e];
        int4 d4 = *(const int4*)&dst[e];
        cl[atomicAdd(&cur[d4.x], 1)] = (uint16_t)s4.x;
        cl[atomicAdd(&cur[d4.y], 1)] = (uint16_t)s4.y;
        cl[atomicAdd(&cur[d4.z], 1)] = (uint16_t)s4.z;
        cl[atomicAdd(&cur[d4.w], 1)] = (uint16_t)s4.w;
    }
}

// ---------------- weight prep: Wt[l][c][k] = (f16)W_l[k][c] ----------------
__global__ __launch_bounds__(256) void k_wprep(const float* __restrict__ W0,
                                               const float* __restrict__ W1,
                                               const float* __restrict__ W2,
                                               f16* __restrict__ Wt) {
    const float* W = (blockIdx.x == 0) ? W0 : (blockIdx.x == 1) ? W1 : W2;
    f16* dst = Wt + blockIdx.x * 16384;
    for (int idx = threadIdx.x; idx < 16384; idx += 256) {
        int c = idx >> 7, k = idx & 127;
        dst[idx] = (f16)W[k * 128 + c];
    }
}

// ---------------- MFMA GEMM v3: W staged once, loop over row tiles ----------------
template <bool F32IN>
__global__ __launch_bounds__(256) void k_gemm(const void* __restrict__ in_,
                                              const f16* __restrict__ Wt,  // [c][k]
                                              const float* __restrict__ dinv,
                                              f16* __restrict__ g) {
    __shared__ f16 Ws[128 * LDA];
    __shared__ f16 As[64 * LDA];
    int b = blockIdx.x;
    int t = b & 31;
    int strip = b >> 5;
    int tid = threadIdx.x;

    // stage Wt -> Ws ONCE (first barrier is inside the tile loop)
    {
        int c = tid >> 1, hf = tid & 1;
        const f16* src = Wt + c * 128 + hf * 64;
        f16* dst = Ws + c * LDA + hf * 64;
#pragma unroll
        for (int j = 0; j < 8; ++j) *(f16x8*)&dst[j * 8] = *(const f16x8*)&src[j * 8];
    }

    int w = tid >> 6, lane = tid & 63;
    int m = lane & 15, q = lane >> 4;
    int rw = w * 16;
    int sr = tid >> 2, skq = (tid & 3) * 32;   // staging row / k-quarter

    for (int tile = strip; tile < 79; tile += STRIPS) {
        int r0 = tile * 64;
        // stage A
        {
            bool valid = (r0 + sr) < N_;
            f16* dst = As + sr * LDA + skq;
            if (F32IN) {
                const float* src = (const float*)in_ + ((size_t)(t * N_ + r0 + sr)) * H_ + skq;
#pragma unroll
                for (int j = 0; j < 8; ++j) {
                    float4 v = valid ? *(const float4*)&src[j * 4] : make_float4(0.f, 0.f, 0.f, 0.f);
                    dst[j * 4 + 0] = (f16)v.x;
                    dst[j * 4 + 1] = (f16)v.y;
                    dst[j * 4 + 2] = (f16)v.z;
                    dst[j * 4 + 3] = (f16)v.w;
                }
            } else {
                const f16* src = (const f16*)in_ + ((size_t)(t * N_ + r0 + sr)) * H_ + skq;
#pragma unroll
                for (int j = 0; j < 4; ++j) {
                    f16x8 v = {};
                    if (valid) v = *(const f16x8*)&src[j * 8];
                    *(f16x8*)&dst[j * 8] = v;
                }
            }
        }
        __syncthreads();  // A (and Ws on first iter) visible

        f32x4 acc[8];
#pragma unroll
        for (int n = 0; n < 8; ++n) acc[n] = (f32x4){0.f, 0.f, 0.f, 0.f};
#pragma unroll
        for (int kb = 0; kb < 4; ++kb) {
            f16x8 aF = *(const f16x8*)&As[(rw + m) * LDA + kb * 32 + q * 8];
#pragma unroll
            for (int n = 0; n < 8; ++n) {
                f16x8 bF = *(const f16x8*)&Ws[(n * 16 + m) * LDA + kb * 32 + q * 8];
                acc[n] = __builtin_amdgcn_mfma_f32_16x16x32_f16(aF, bF, acc[n], 0, 0, 0);
            }
        }
        __syncthreads();  // done reading As; reuse for epilogue

#pragma unroll
        for (int i = 0; i < 4; ++i) {
            int rr = rw + q * 4 + i;
            int gr = r0 + rr;
            float d = dinv[t * N_ + (gr < N_ ? gr : N_ - 1)];
#pragma unroll
            for (int n = 0; n < 8; ++n)
                As[rr * LDA + n * 16 + m] = (f16)(acc[n][i] * d);
        }
        __syncthreads();
        if (r0 + sr < N_) {
            f16* dst = g + ((size_t)(t * N_ + r0 + sr)) * H_ + skq;
            const f16* src = As + sr * LDA + skq;
#pragma unroll
            for (int j = 0; j < 4; ++j) *(f16x8*)&dst[j * 8] = *(const f16x8*)&src[j * 8];
        }
        __syncthreads();  // As free for next tile's staging
    }
}

// ---------------- CSR gather v4 ----------------
// (1) Graph-major per-XCD block order: XCD = blk&7 (HW round-robin); the j-th
//     block on an XCD maps to graph x+8*(j/NBLK_), node-block j%NBLK_. One
//     graph's gather set (~2.7MB) stays resident in the 4MB XCD L2.
// (2) 8-aligned edge chunks: one dwordx4 col load per 8 edges (prefetched one
//     chunk ahead), no index clamping; out-of-range lanes redirected via ONE
//     cndmask to a known-zero row (the z buffer: zeroed by k_scan, first
//     written by k_reduce AFTER all aggr calls; it sits exactly 2*BIG f16
//     after P16 -> row index 320000-5000*t from gg). Adds unconditional.
__global__ __launch_bounds__(256) void k_aggr(const int* __restrict__ ptr,
                                              const uint16_t* __restrict__ col,
                                              const f16* __restrict__ g,
                                              const float* __restrict__ dinv,
                                              const float* __restrict__ b,
                                              f16* __restrict__ out) {
    int x = blockIdx.x & 7;
    int j = blockIdx.x >> 3;
    int gsel = j / NBLK_;
    int nb = j - gsel * NBLK_;
    int t = x + (gsel << 3);

    int w = threadIdx.x >> 6;
    int lane = threadIdx.x & 63;
    int q = lane >> 4, m = lane & 15;
    int n0 = nb * 16 + w * 4;    // wave's first node (4-aligned)
    if (n0 >= N_) return;        // tail waves (no barriers in this kernel)
    int base = t * N_;
    const f16* gg = g + (size_t)base * H_;
    const uint16_t* cl = col + (size_t)t * E_;
    int n = n0 + q;              // this 16-lane group's node
    unsigned moB = (unsigned)(m * 8);   // lane's 8-col slice (element offset)

    // CSR bounds for the wave's 4 nodes: one aligned int4 + one scalar
    int4 p4 = *(const int4*)&ptr[base + n0];
    int pend = (n0 + 4 < N_) ? ptr[base + n0 + 4] : E_;
    int begin = (q == 0) ? p4.x : (q == 1) ? p4.y : (q == 2) ? p4.z : p4.w;
    int end   = (q == 0) ? p4.y : (q == 1) ? p4.z : (q == 2) ? p4.w : pend;

    // epilogue operands hoisted (overlap with gathers)
    float dn = dinv[base + n];
    float4 b4a = *(const float4*)&b[m * 8];
    float4 b4b = *(const float4*)&b[m * 8 + 4];

    // zero-row index relative to gg (see header comment; layout-coupled!)
    int zidx = 320000 - 5000 * t;

    f16x8 a0 = *(const f16x8*)&gg[((unsigned)n << 7) + moB];  // self-loop row
    f16x8 a1 = {}, a2 = {}, a3 = {}, a4 = {}, a5 = {}, a6 = {}, a7 = {};

    int e0 = begin & ~7;
    int elast = (end - 1) & ~7;          // last chunk start (unused if deg==0)
    unsigned span = (unsigned)(end - begin);
    uint4 cc = *(const uint4*)&cl[e0];   // 16B-aligned; always valid ws memory
    for (int e = e0; e < end; e += 8) {
        int en = e + 8;
        int epf = en < elast ? en : elast;
        uint4 cn = *(const uint4*)&cl[epf];   // prefetch next chunk's cols
        unsigned eb = (unsigned)(e - begin);  // wraps on first chunk; cmp trick ok
        int i0 = (int)(cc.x & 0xFFFFu), i1 = (int)(cc.x >> 16);
        int i2 = (int)(cc.y & 0xFFFFu), i3 = (int)(cc.y >> 16);
        int i4 = (int)(cc.z & 0xFFFFu), i5 = (int)(cc.z >> 16);
        int i6 = (int)(cc.w & 0xFFFFu), i7 = (int)(cc.w >> 16);
        int s0 = (eb + 0 < span) ? i0 : zidx;
        int s1 = (eb + 1 < span) ? i1 : zidx;
        int s2 = (eb + 2 < span) ? i2 : zidx;
        int s3 = (eb + 3 < span) ? i3 : zidx;
        int s4 = (eb + 4 < span) ? i4 : zidx;
        int s5 = (eb + 5 < span) ? i5 : zidx;
        int s6 = (eb + 6 < span) ? i6 : zidx;
        int s7 = (eb + 7 < span) ? i7 : zidx;
        f16x8 v0 = *(const f16x8*)&gg[((unsigned)s0 << 7) + moB];
        f16x8 v1 = *(const f16x8*)&gg[((unsigned)s1 << 7) + moB];
        f16x8 v2 = *(const f16x8*)&gg[((unsigned)s2 << 7) + moB];
        f16x8 v3 = *(const f16x8*)&gg[((unsigned)s3 << 7) + moB];
        f16x8 v4 = *(const f16x8*)&gg[((unsigned)s4 << 7) + moB];
        f16x8 v5 = *(const f16x8*)&gg[((unsigned)s5 << 7) + moB];
        f16x8 v6 = *(const f16x8*)&gg[((unsigned)s6 << 7) + moB];
        f16x8 v7 = *(const f16x8*)&gg[((unsigned)s7 << 7) + moB];
        a0 += v0; a1 += v1; a2 += v2; a3 += v3;
        a4 += v4; a5 += v5; a6 += v6; a7 += v7;
        cc = cn;
    }
    a0 += a1; a2 += a3; a4 += a5; a6 += a7;
    a0 += a2; a4 += a6;
    a0 += a4;

    f16x8 o;
#pragma unroll
    for (int jj = 0; jj < 8; ++jj) {
        float bj = (jj < 4) ? ((const float*)&b4a)[jj] : ((const float*)&b4b)[jj - 4];
        o[jj] = (f16)fast_tanh(dn * (float)a0[jj] + bj);
    }
    *(f16x8*)&out[((size_t)base + n) * H_ + moB] = o;  // contiguous 1 KB wave store
}

// ---------------- node-sum: z[t][c] = sum_n h[t][n][c] ----------------
__global__ __launch_bounds__(256) void k_reduce(const f16* __restrict__ h, float* __restrict__ z) {
    int t = blockIdx.x, seg = blockIdx.y;
    int tid = threadIdx.x;
    int rg = tid >> 5;
    int c = (tid & 31) * 4;
    const f16* p = h + (size_t)t * N_ * H_;
    float4 acc = make_float4(0.f, 0.f, 0.f, 0.f);
    int n0 = seg * 500;
    for (int n = n0 + rg; n < n0 + 500; n += 8) {
        f16x4 v = *(const f16x4*)&p[(size_t)n * H_ + c];
        acc.x += (float)v[0]; acc.y += (float)v[1]; acc.z += (float)v[2]; acc.w += (float)v[3];
    }
    __shared__ float4 part[256];
    part[tid] = acc;
    __syncthreads();
    if (rg == 0) {
        float4 s = part[tid];
#pragma unroll
        for (int j = 1; j < 8; ++j) {
            float4 v = part[(j << 5) + tid];
            s.x += v.x; s.y += v.y; s.z += v.z; s.w += v.w;
        }
        atomicAdd(&z[t * H_ + c + 0], s.x);
        atomicAdd(&z[t * H_ + c + 1], s.y);
        atomicAdd(&z[t * H_ + c + 2], s.z);
        atomicAdd(&z[t * H_ + c + 3], s.w);
    }
}

// ---------------- head stage 1: q,k,v ----------------
__global__ __launch_bounds__(128) void k_qkv(const float* __restrict__ z,
                                             const float* __restrict__ Wq, const float* __restrict__ bq,
                                             const float* __restrict__ Wk, const float* __restrict__ bk,
                                             const float* __restrict__ Wv, const float* __restrict__ bv,
                                             float* __restrict__ q, float* __restrict__ k,
                                             float* __restrict__ v) {
    int t = blockIdx.x, c = threadIdx.x;
    __shared__ float zs[128];
    zs[c] = z[t * 128 + c];
    __syncthreads();
    float aq = bq[c], ak = bk[c], av = bv[c];
    for (int kk = 0; kk < 128; ++kk) {
        float zv = zs[kk];
        aq += zv * Wq[(kk << 7) + c];
        ak += zv * Wk[(kk << 7) + c];
        av += zv * Wv[(kk << 7) + c];
    }
    q[t * 128 + c] = aq;
    k[t * 128 + c] = ak;
    v[t * 128 + c] = av;
}

// ---------------- head stage 2 ----------------
__global__ __launch_bounds__(256) void k_attnmid(
    const float* __restrict__ q, const float* __restrict__ k, const float* __restrict__ v,
    const float* __restrict__ Wo, const float* __restrict__ bo,
    const float* __restrict__ g2, const float* __restrict__ beta2,
    const float* __restrict__ Wm1, const float* __restrict__ bm1,
    const float* __restrict__ Wm2, const float* __restrict__ bm2,
    float* __restrict__ xr) {
    int t = blockIdx.x, tid = threadIdx.x;
    __shared__ float Ks[32 * 128], Vs[32 * 128];
    __shared__ float qs[128], sc[8 * 32], xa[128], hid[512], ys[128];
    __shared__ float redA[128], redB[128];

    for (int i = tid; i < 32 * 128; i += 256) { Ks[i] = k[i]; Vs[i] = v[i]; }
    if (tid < 128) qs[tid] = q[t * 128 + tid];
    __syncthreads();

    {
        int h = tid >> 5, s = tid & 31;
        float d = 0.0f;
#pragma unroll
        for (int kk = 0; kk < 16; ++kk)
            d += qs[(h << 4) + kk] * Ks[(s << 7) + (h << 4) + kk];
        sc[tid] = d * 0.25f;
    }
    __syncthreads();
    if (tid < 8) {
        float m = -1e30f;
        for (int s = 0; s < 32; ++s) m = fmaxf(m, sc[(tid << 5) + s]);
        float l = 0.0f;
        for (int s = 0; s < 32; ++s) { float e = __expf(sc[(tid << 5) + s] - m); sc[(tid << 5) + s] = e; l += e; }
        float inv = 1.0f / l;
        for (int s = 0; s < 32; ++s) sc[(tid << 5) + s] *= inv;
    }
    __syncthreads();
    if (tid < 128) {
        int h = tid >> 4;
        float o = 0.0f;
        for (int s = 0; s < 32; ++s) o += sc[(h << 5) + s] * Vs[(s << 7) + tid];
        qs[tid] = o;
    }
    __syncthreads();
    if (tid < 128) {
        float a = bo[tid];
        for (int kk = 0; kk < 128; ++kk) a += qs[kk] * Wo[(kk << 7) + tid];
        xa[tid] = a;
    }
    __syncthreads();
    for (int j = tid; j < 512; j += 256) {
        float a = bm1[j];
        for (int kk = 0; kk < 128; ++kk) a += xa[kk] * Wm1[(kk << 9) + j];
        hid[j] = fmaxf(a, 0.0f);
    }
    __syncthreads();
    if (tid < 128) {
        float a = bm2[tid];
        for (int j = 0; j < 512; ++j) a += hid[j] * Wm2[(j << 7) + tid];
        ys[tid] = xa[tid] + a;
    }
    __syncthreads();
    if (tid < 128) { redA[tid] = ys[tid]; redB[tid] = ys[tid] * ys[tid]; }
    __syncthreads();
    for (int off = 64; off > 0; off >>= 1) {
        if (tid < off) { redA[tid] += redA[tid + off]; redB[tid] += redB[tid + off]; }
        __syncthreads();
    }
    float mu = redA[0] * (1.0f / 128.0f);
    float var = redB[0] * (1.0f / 128.0f) - mu * mu;
    float rs = rsqrtf(var + 1e-5f);
    if (tid < 128) {
        float yv = (ys[tid] - mu) * rs * g2[tid] + beta2[tid];
        xr[t * 128 + tid] = fmaxf(yv, 0.0f);
    }
}

// ---------------- head stage 3 ----------------
__global__ __launch_bounds__(128) void k_final(const float* __restrict__ xr,
                                               const float* __restrict__ Wl,
                                               const float* __restrict__ bl,
                                               float* __restrict__ out) {
    int tid = threadIdx.x;
    __shared__ float pooled[128];
    float s = 0.0f;
    for (int t = 0; t < 32; ++t) s += xr[t * 128 + tid];
    pooled[tid] = s;
    __syncthreads();
    if (tid < C_) {
        float a = bl[tid];
        for (int kk = 0; kk < 128; ++kk) a += pooled[kk] * Wl[kk * C_ + tid];
        out[tid] = a;
    }
}

extern "C" void kernel_launch(void* const* d_in, const int* in_sizes, int n_in,
                              void* d_out, int out_size, void* d_ws, size_t ws_size,
                              hipStream_t stream) {
    const float* x  = (const float*)d_in[0];
    const int*   ei = (const int*)d_in[1];
    const float* W0 = (const float*)d_in[2];  const float* b0 = (const float*)d_in[3];
    const float* W1 = (const float*)d_in[4];  const float* b1 = (const float*)d_in[5];
    const float* W2 = (const float*)d_in[6];  const float* b2 = (const float*)d_in[7];
    const float* Wq = (const float*)d_in[8];  const float* bq = (const float*)d_in[9];
    const float* Wk = (const float*)d_in[10]; const float* bk = (const float*)d_in[11];
    const float* Wv = (const float*)d_in[12]; const float* bv = (const float*)d_in[13];
    const float* Wo = (const float*)d_in[14]; const float* bo = (const float*)d_in[15];
    const float* g2 = (const float*)d_in[16]; const float* beta2 = (const float*)d_in[17];
    const float* Wm1 = (const float*)d_in[18]; const float* bm1 = (const float*)d_in[19];
    const float* Wm2 = (const float*)d_in[20]; const float* bm2 = (const float*)d_in[21];
    const float* Wl = (const float*)d_in[22]; const float* bl = (const float*)d_in[23];
    float* outp = (float*)d_out;

    const size_t BIG = (size_t)T_ * N_ * H_;
    char* ws = (char*)d_ws;
    float*    dinv = (float*)(ws);
    int*      ptr  = (int*)(ws + 640000);
    uint16_t* col  = (uint16_t*)(ws + 1280000);
    f16*      Wt   = (f16*)(ws + 6400000);
    f16*      P16  = (f16*)(ws + 6498304);
    f16*      Q16  = P16 + BIG;
    float*    z    = (float*)(Q16 + BIG);   // NOTE: k_aggr's zero-row aliases z[0..63]
    float*    zq   = z + 4096;
    float*    zk   = zq + 4096;
    float*    zv   = zk + 4096;
    float*    xr   = zv + 4096;
    int*      part = (int*)P16;   // CSR partials alias P16 (used only before first gemm)

    k_wprep<<<3, 256, 0, stream>>>(W0, W1, W2, Wt);
    k_count<<<NB_ * 32, 256, 0, stream>>>(ei, part);
    k_scan<<<T_, 256, 0, stream>>>(part, ptr, dinv, z);
    k_scatter<<<NB_ * 32, 256, 0, stream>>>(ei, part, col);

    const float* bl_[3] = {b0, b1, b2};
    const int AGGR_BLOCKS = NBLK_ * 32;   // 16 nodes/block, 4 nodes/wave
    k_gemm<true><<<STRIPS * 32, 256, 0, stream>>>(x, Wt, dinv, P16);
    k_aggr<<<AGGR_BLOCKS, 256, 0, stream>>>(ptr, col, P16, dinv, bl_[0], Q16);
    k_gemm<false><<<STRIPS * 32, 256, 0, stream>>>(Q16, Wt + 16384, dinv, P16);
    k_aggr<<<AGGR_BLOCKS, 256, 0, stream>>>(ptr, col, P16, dinv, bl_[1], Q16);
    k_gemm<false><<<STRIPS * 32, 256, 0, stream>>>(Q16, Wt + 32768, dinv, P16);
    k_aggr<<<AGGR_BLOCKS, 256, 0, stream>>>(ptr, col, P16, dinv, bl_[2], Q16);

    k_reduce<<<dim3(T_, 10), 256, 0, stream>>>(Q16, z);

    k_qkv<<<T_, 128, 0, stream>>>(z, Wq, bq, Wk, bk, Wv, bv, zq, zk, zv);
    k_attnmid<<<T_, 256, 0, stream>>>(zq, zk, zv, Wo, bo, g2, beta2,
                                      Wm1, bm1, Wm2, bm2, xr);
    k_final<<<1, 128, 0, stream>>>(xr, Wl, bl, outp);
}